// Round 6
// baseline (272.920 us; speedup 1.0000x reference)
//
#include <hip/hip_runtime.h>
#include <stdint.h>

// RPN rotated-NMS post-processor, MI355X. Round 6: LDS-resident blocked NMS
// (transposed staged mask, skip-dead diag), sort+decode fusion, iou writes
// mask rows from LDS (no global atomics / no mask memset). 7 graph nodes.

#define NBATCH 4
#define AANCH 15
#define HDIM 200
#define WDIM 200
#define MTOT (AANCH*HDIM*WDIM)   // 600000
#define KTOP 1000
#define POSTN 300
#define NBINS 16384
#define CAND_CAP 2048
#define NWORDS 16                // ceil(1000/64)
#define NMS_TH 0.7f
#define BPB 75                   // blocks per batch for hist
#define CHUNK (MTOT/BPB)         // 8000
#define IOU_BPB 125              // iou blocks per batch
#define IOU_WPB 128              // mask words per iou block (8 i-rows x 16)
#define QCAP (IOU_WPB*64)        // 8192: provable max survivors per block
#define TSTR 1025                // transposed-mask LDS row stride (pad +1 ... +25)

// ---------------- ws layout ----------------
constexpr size_t OFF_HIST = 0;
constexpr size_t SZ_HIST  = (size_t)NBATCH*NBINS*4;                 // 262144
constexpr size_t OFF_CNT  = OFF_HIST + SZ_HIST;
constexpr size_t OFF_THR  = OFF_CNT + 256;
constexpr size_t OFF_CAND = OFF_THR + 256;
constexpr size_t OFF_PROP = OFF_CAND + (size_t)NBATCH*CAND_CAP*8;
constexpr size_t OFF_SCORE= OFF_PROP + (size_t)NBATCH*KTOP*5*4;
constexpr size_t OFF_CORN = OFF_SCORE+ (size_t)NBATCH*KTOP*4;
constexpr size_t OFF_AREA = OFF_CORN + (size_t)NBATCH*KTOP*8*4;
constexpr size_t OFF_VALID= OFF_AREA + (size_t)NBATCH*KTOP*4;
constexpr size_t OFF_XYR  = OFF_VALID+ (size_t)NBATCH*KTOP*4;
constexpr size_t OFF_MASK = OFF_XYR  + (size_t)NBATCH*KTOP*16;
constexpr size_t SZ_MASK  = (size_t)NBATCH*KTOP*NWORDS*8;           // 512000

__device__ __forceinline__ float sigmoid_ref(float x) {
  return 1.0f / (1.0f + expf(-x));
}

// ---------------- histogram: LDS-privatized ----------------
__global__ __launch_bounds__(256) void k_hist(const float* __restrict__ obj,
                                              uint32_t* __restrict__ hist) {
  __shared__ uint32_t h[NBINS];
  for (int i = threadIdx.x; i < NBINS; i += 256) h[i] = 0;
  __syncthreads();
  int n = blockIdx.x / BPB, c = blockIdx.x % BPB;
  const float4* p = (const float4*)(obj + (size_t)n*MTOT + (size_t)c*CHUNK);
  const int nq = CHUNK/4;
  for (int q = threadIdx.x; q < nq; q += 256) {
    float4 v = p[q];
    #pragma unroll
    for (int k = 0; k < 4; ++k) {
      float x = (&v.x)[k];
      uint32_t bits = __float_as_uint(sigmoid_ref(x));
      uint32_t bin = bits >> 16; if (bin > NBINS-1) bin = NBINS-1;
      atomicAdd(&h[bin], 1u);
    }
  }
  __syncthreads();
  for (int i = threadIdx.x; i < NBINS; i += 256) {
    uint32_t v = h[i];
    if (v) atomicAdd(&hist[n*NBINS + i], v);
  }
}

// ---------------- threshold ----------------
__global__ __launch_bounds__(256) void k_thresh(const uint32_t* __restrict__ hist,
                                                uint32_t* __restrict__ thr) {
  __shared__ uint32_t ps[256];
  int n = blockIdx.x, tid = threadIdx.x;
  uint32_t s = 0;
  const uint32_t* hb = &hist[n*NBINS];
  #pragma unroll 4
  for (int b = tid*64; b < tid*64+64; ++b) s += hb[b];
  ps[tid] = s;
  __syncthreads();
  if (tid == 0) {
    uint32_t cum = 0; int cidx = -1;
    for (int cc = 255; cc >= 0; --cc) {
      if (cum + ps[cc] >= KTOP) { cidx = cc; break; }
      cum += ps[cc];
    }
    if (cidx < 0) { thr[n] = 0u; return; }
    int b = cidx*64+63;
    for (; b >= cidx*64; --b) { cum += hb[b]; if (cum >= KTOP) break; }
    thr[n] = (uint32_t)(b < 0 ? 0 : b);
  }
}

// ---------------- compact candidates (wave-aggregated atomics) ----------------
__global__ __launch_bounds__(256) void k_compact(const float* __restrict__ obj,
                                                 const uint32_t* __restrict__ thr,
                                                 uint64_t* __restrict__ cand,
                                                 uint32_t* __restrict__ cnt) {
  int t = blockIdx.x*blockDim.x + threadIdx.x;
  if (t >= NBATCH*MTOT) return;
  int n = t / MTOT;           // wave-uniform: MTOT % 64 == 0
  int rem = t % MTOT;
  int lane = threadIdx.x & 63;
  float x = obj[t];
  uint32_t bits = __float_as_uint(sigmoid_ref(x));
  uint32_t bin = bits >> 16; if (bin > NBINS-1) bin = NBINS-1;
  bool hit = (bin >= thr[n]);
  unsigned long long bal = __ballot(hit);
  if (!bal) return;
  int tot = __popcll(bal);
  int leader = __ffsll(bal) - 1;
  uint32_t base = 0;
  if (lane == leader) base = atomicAdd(&cnt[n], (uint32_t)tot);
  base = __shfl(base, leader);
  if (hit) {
    uint32_t p = base + (uint32_t)__popcll(bal & ((1ull << lane) - 1ull));
    if (p < CAND_CAP) {
      int hw = rem % (HDIM*WDIM);
      int a  = rem / (HDIM*WDIM);
      uint32_t fidx = (uint32_t)(hw*AANCH + a);
      cand[(size_t)n*CAND_CAP + p] = ((uint64_t)bits << 32) | (uint32_t)(~fidx);
    }
  }
}

// ---------------- bitonic sort (2048) + fused decode epilogue ----------------
__global__ __launch_bounds__(1024) void k_sortdec(const uint64_t* __restrict__ cand,
                                                  const uint32_t* __restrict__ cnt,
                                                  const float* __restrict__ breg,
                                                  const float* __restrict__ anch,
                                                  float* __restrict__ prop,
                                                  float* __restrict__ score,
                                                  float* __restrict__ corn,
                                                  float* __restrict__ area,
                                                  float4* __restrict__ xyr,
                                                  uint32_t* __restrict__ validf) {
  __shared__ uint64_t sk[CAND_CAP];
  int n = blockIdx.x, tid = threadIdx.x;
  uint32_t c = cnt[n]; if (c > CAND_CAP) c = CAND_CAP;
  #pragma unroll
  for (int i = tid; i < CAND_CAP; i += 1024)
    sk[i] = (i < (int)c) ? cand[(size_t)n*CAND_CAP + i] : 0ull;
  __syncthreads();
  for (int len = 2; len <= CAND_CAP; len <<= 1) {
    for (int str = len >> 1; str > 0; str >>= 1) {
      #pragma unroll
      for (int i = tid; i < CAND_CAP; i += 1024) {
        int j = i ^ str;
        if (j > i) {
          bool up = ((i & len) == 0);
          uint64_t x = sk[i], y = sk[j];
          if ((x > y) == up) { sk[i] = y; sk[j] = x; }
        }
      }
      __syncthreads();
    }
  }
  // ---- decode entry `tid` (rank tid, descending) ----
  if (tid < KTOP) {
#pragma clang fp contract(off)
    int t = n*KTOP + tid;
    uint64_t key = sk[CAND_CAP-1-tid];
    uint32_t idx = ~(uint32_t)(key & 0xFFFFFFFFull);
    float s = __uint_as_float((uint32_t)(key >> 32));
    int a = idx % AANCH, pos = idx / AANCH;
    int w = pos % WDIM, h = pos / WDIM;
    float d[5], an[5];
    #pragma unroll
    for (int j = 0; j < 5; ++j)
      d[j] = breg[((n*(AANCH*5) + (a*5+j))*HDIM + h)*WDIM + w];
    #pragma unroll
    for (int j = 0; j < 5; ++j)
      an[j] = anch[((size_t)n*MTOT + idx)*5 + j];
    const float CLIP = 4.135166556742356f;           // log(1000/16)
    float dw = fminf(d[2], CLIP), dh = fminf(d[3], CLIP);
    float x  = d[0]*an[2] + an[0];
    float y  = d[1]*an[3] + an[1];
    float bw = expf(dw)*an[2];
    float bh = expf(dh)*an[3];
    float th = an[4] + d[4]*57.29577951308232f;      // 180/pi
    prop[t*5+0]=x; prop[t*5+1]=y; prop[t*5+2]=bw; prop[t*5+3]=bh; prop[t*5+4]=th;
    score[t] = s;
    validf[t] = (bw >= 4.0f && bh >= 4.0f) ? 1u : 0u;
    area[t] = bw*bh;
    float r = 0.5f*sqrtf(bw*bw + bh*bh);
    xyr[t] = make_float4(x, y, r, 0.0f);
    float ang = th * 0.017453292519943295f;          // pi/180
    float cs = cosf(ang), sn = sinf(ang);
    float hw2 = bw*0.5f, hh2 = bh*0.5f;
    const float sx[4] = {1.f,-1.f,-1.f,1.f};
    const float sy[4] = {1.f,1.f,-1.f,-1.f};
    #pragma unroll
    for (int k = 0; k < 4; ++k) {
      float dxk = sx[k]*hw2, dyk = sy[k]*hh2;
      float cx = (x + cs*dxk) - sn*dyk;
      float cy = (y + sn*dxk) + cs*dyk;
      corn[t*8 + k*2 + 0] = cx;
      corn[t*8 + k*2 + 1] = cy;
    }
  }
}

// ---------------- Sutherland-Hodgman (mirrors reference arithmetic) ----------------
__device__ float quad_inter_area(const float* __restrict__ ca, const float* __restrict__ cb) {
#pragma clang fp contract(off)
  float px[8], py[8];
  int n = 4;
  #pragma unroll
  for (int i = 0; i < 4; ++i) { px[i] = ca[2*i]; py[i] = ca[2*i+1]; }
  for (int e = 0; e < 4; ++e) {
    float p1x = cb[2*e], p1y = cb[2*e+1];
    int e2 = (e+1)&3;
    float dx = cb[2*e2] - p1x, dy = cb[2*e2+1] - p1y;
    float sd[8];
    for (int i = 0; i < n; ++i)
      sd[i] = dx*(py[i]-p1y) - dy*(px[i]-p1x);
    float qx[8], qy[8];
    int m = 0;
    for (int i = 0; i < n; ++i) {
      int nx = (i+1 < n) ? i+1 : 0;
      bool ini = sd[i] >= 0.0f, inn = sd[nx] >= 0.0f;
      if (ini) { qx[m]=px[i]; qy[m]=py[i]; ++m; }
      if (ini != inn) {
        float den = sd[i]-sd[nx];
        float dd = (fabsf(den) < 1e-12f) ? 1e-12f : den;
        float tt = sd[i]/dd;
        qx[m] = px[i] + tt*(px[nx]-px[i]);
        qy[m] = py[i] + tt*(py[nx]-py[i]);
        ++m;
      }
    }
    n = m;
    for (int i = 0; i < n; ++i) { px[i]=qx[i]; py[i]=qy[i]; }
    if (n == 0) break;
  }
  float ssum = 0.0f;
  for (int i = 0; i < n; ++i) {
    int nx = (i+1 < n) ? i+1 : 0;
    ssum += px[i]*py[nx] - px[nx]*py[i];
  }
  return 0.5f*fabsf(ssum);
}

// ---------------- fused circle-test + clip; block owns 8 mask rows in LDS ----------------
__global__ __launch_bounds__(256) void k_iou(const float4* __restrict__ xyr,
                                             const float* __restrict__ corn,
                                             const float* __restrict__ area,
                                             uint64_t* __restrict__ mask) {
  __shared__ uint32_t q[QCAP];            // 32 KB
  __shared__ uint32_t qcnt;
  __shared__ uint32_t mrow32[IOU_WPB*2];  // 8 rows x 16 words, as 32-bit halves
  __shared__ float ca8[64];               // 8 rows' corners
  __shared__ float aa8[8];
  int n = blockIdx.x / IOU_BPB;
  int wbase = (blockIdx.x % IOU_BPB) * IOU_WPB;
  int i0 = wbase >> 4;                    // first owned i-row
  int wv = threadIdx.x >> 6, lane = threadIdx.x & 63;
  if (threadIdx.x == 0) qcnt = 0;
  if (threadIdx.x < IOU_WPB*2) mrow32[threadIdx.x] = 0;
  if (threadIdx.x < 64) ca8[threadIdx.x] = corn[(size_t)(n*KTOP + i0)*8 + threadIdx.x];
  if (threadIdx.x >= 64 && threadIdx.x < 72) aa8[threadIdx.x-64] = area[n*KTOP + i0 + threadIdx.x-64];
  __syncthreads();
  for (int w = wv; w < IOU_WPB; w += 4) {
    int word = wbase + w;
    int i = word >> 4;               // word / NWORDS
    int jb = word & 15;              // word % NWORDS
    if (jb*64 + 63 <= i) continue;   // no j > i in this word
    int j = jb*64 + lane;
    bool hit = false;
    if (j > i && j < KTOP) {
      float4 a = xyr[n*KTOP + i];    // wave-uniform
      float4 b = xyr[n*KTOP + j];    // coalesced 16B/lane
      float dx = a.x - b.x, dy = a.y - b.y;
      float rs = a.z + b.z;
      hit = (dx*dx + dy*dy) <= rs*rs*1.0001f;
    }
    unsigned long long bal = __ballot(hit);
    if (!bal) continue;
    int tot = __popcll(bal);
    int leader = __ffsll(bal) - 1;
    uint32_t base = 0;
    if (lane == leader) base = atomicAdd(&qcnt, (uint32_t)tot);
    base = __shfl(base, leader);
    if (hit) {
      int pos = __popcll(bal & ((1ull << lane) - 1ull));
      q[base + pos] = ((uint32_t)i << 10) | (uint32_t)j;
    }
  }
  __syncthreads();
  uint32_t cnt = qcnt;
  for (uint32_t t = threadIdx.x; t < cnt; t += 256) {
    uint32_t code = q[t];
    int i = code >> 10, j = code & 1023;
    int bj = n*KTOP + j;
    float inter = quad_inter_area(&ca8[(i - i0)*8], &corn[(size_t)bj*8]);
    float uni = (aa8[i - i0] + area[bj]) - inter;
    if (inter / fmaxf(uni, 1e-8f) > NMS_TH)
      atomicOr(&mrow32[((i - i0)*NWORDS + (j >> 6))*2 + ((j >> 5) & 1)],
               1u << (j & 31));
  }
  __syncthreads();
  // store the block's 128 contiguous mask words (full overwrite, no atomics)
  uint64_t* dst = &mask[(size_t)n*KTOP*NWORDS + wbase];
  for (int t = threadIdx.x; t < IOU_WPB; t += 256)
    dst[t] = (uint64_t)mrow32[t*2] | ((uint64_t)mrow32[t*2+1] << 32);
}

// ---------------- blocked greedy NMS, fully LDS-resident + fused output ----------------
__global__ __launch_bounds__(256) void k_nms(const uint32_t* __restrict__ validf,
                                             const uint64_t* __restrict__ mask,
                                             const float* __restrict__ prop,
                                             const float* __restrict__ score,
                                             float* __restrict__ out) {
  __shared__ uint64_t smT[NWORDS*TSTR];   // 131200 B, transposed [word][row]
  __shared__ uint64_t kw[NWORDS];
  int n = blockIdx.x;
  int tid = threadIdx.x, wv = tid >> 6, lane = tid & 63;
  const uint64_t* M = &mask[(size_t)n*KTOP*NWORDS];
  // stage transposed: coalesced global reads, conflict-spread LDS writes
  for (int g = tid; g < KTOP*NWORDS; g += 256) {
    int row = g >> 4, l = g & 15;
    smT[l*TSTR + row] = M[g];
  }
  if (wv == 0) {
    #pragma unroll
    for (int w = 0; w < NWORDS; ++w) {
      int k = w*64 + lane;
      uint32_t v = (k < KTOP) ? validf[n*KTOP + k] : 0u;
      unsigned long long b = __ballot(v != 0u);
      if (lane == 0) kw[w] = (uint64_t)b;
    }
  }
  __syncthreads();

  for (int b = 0; b < NWORDS; ++b) {
    // --- diagonal resolve (wave 0), skip dead rows ---
    if (wv == 0) {
      int row = b*64 + lane;
      uint64_t diag = (row < KTOP) ? smT[b*TSTR + row] : 0ull;
      uint64_t alive = kw[b];
      uint64_t rem = alive;                 // alive rows not yet processed
      while (rem) {
        int i = __ffsll((unsigned long long)rem) - 1;
        uint64_t d = __shfl(diag, i);       // bits strictly > i
        alive &= ~d;
        rem &= ~d;
        rem &= rem - 1;                     // clear bit i
      }
      if (lane == 0) kw[b] = alive;
    }
    __syncthreads();
    if (b == NWORDS-1) break;
    uint64_t alive = kw[b];
    // --- cross-block apply: words l in (b, NWORDS), 4 waves round-robin ---
    int row = b*64 + lane;
    bool me = ((alive >> lane) & 1ull) && (row < KTOP);
    uint64_t mv0=0, mv1=0, mv2=0, mv3=0;
    int l0 = b+1+wv, l1 = l0+4, l2 = l0+8, l3 = l0+12;
    if (me) {
      if (l0 < NWORDS) mv0 = smT[l0*TSTR + row];
      if (l1 < NWORDS) mv1 = smT[l1*TSTR + row];
      if (l2 < NWORDS) mv2 = smT[l2*TSTR + row];
      if (l3 < NWORDS) mv3 = smT[l3*TSTR + row];
    }
    #pragma unroll
    for (int s = 1; s < 64; s <<= 1) {
      mv0 |= __shfl_xor(mv0, s);
      mv1 |= __shfl_xor(mv1, s);
      mv2 |= __shfl_xor(mv2, s);
      mv3 |= __shfl_xor(mv3, s);
    }
    if (lane == 0) {
      if (l0 < NWORDS) kw[l0] &= ~mv0;
      if (l1 < NWORDS) kw[l1] &= ~mv1;
      if (l2 < NWORDS) kw[l2] &= ~mv2;
      if (l3 < NWORDS) kw[l3] &= ~mv3;
    }
    __syncthreads();
  }

  // rank <= POSTN trim (thread 0), then all threads write output
  if (tid == 0) {
    int prev = 0;
    #pragma unroll
    for (int t = 0; t < NWORDS; ++t) {
      uint64_t wrd = kw[t];
      int pc = __popcll(wrd);
      if (prev >= POSTN) wrd = 0;
      else if (prev + pc > POSTN) {
        int allow = POSTN - prev;
        while (__popcll(wrd) > allow) wrd &= ~(1ull << (63 - __clzll(wrd)));
      }
      prev += __popcll(wrd);
      kw[t] = wrd;
    }
  }
  __syncthreads();
  for (int k = tid; k < KTOP; k += 256) {
    bool bb = (kw[k>>6] >> (k&63)) & 1ull;
    float f = bb ? 1.0f : 0.0f;
    int t = n*KTOP + k;
    #pragma unroll
    for (int c = 0; c < 5; ++c) out[t*6 + c] = prop[t*5 + c] * f;
    out[t*6 + 5] = score[t] * f;
  }
}

extern "C" void kernel_launch(void* const* d_in, const int* in_sizes, int n_in,
                              void* d_out, int out_size, void* d_ws, size_t ws_size,
                              hipStream_t stream) {
  const float* obj  = (const float*)d_in[0];
  const float* breg = (const float*)d_in[1];
  const float* anch = (const float*)d_in[2];
  float* out = (float*)d_out;
  char* ws = (char*)d_ws;

  uint32_t* hist  = (uint32_t*)(ws + OFF_HIST);
  uint32_t* cnt   = (uint32_t*)(ws + OFF_CNT);
  uint32_t* thr   = (uint32_t*)(ws + OFF_THR);
  uint64_t* cand  = (uint64_t*)(ws + OFF_CAND);
  float*    prop  = (float*)(ws + OFF_PROP);
  float*    score = (float*)(ws + OFF_SCORE);
  float*    corn  = (float*)(ws + OFF_CORN);
  float*    area  = (float*)(ws + OFF_AREA);
  uint32_t* validf= (uint32_t*)(ws + OFF_VALID);
  float4*   xyr   = (float4*)(ws + OFF_XYR);
  uint64_t* mask  = (uint64_t*)(ws + OFF_MASK);

  hipMemsetAsync(ws, 0, OFF_CAND, stream);   // hist + cnt + thr

  int nt = NBATCH*MTOT;
  k_hist   <<<NBATCH*BPB, 256, 0, stream>>>(obj, hist);
  k_thresh <<<NBATCH, 256, 0, stream>>>(hist, thr);
  k_compact<<<(nt+255)/256, 256, 0, stream>>>(obj, thr, cand, cnt);
  k_sortdec<<<NBATCH, 1024, 0, stream>>>(cand, cnt, breg, anch, prop, score, corn, area, xyr, validf);
  k_iou    <<<NBATCH*IOU_BPB, 256, 0, stream>>>(xyr, corn, area, mask);
  k_nms    <<<NBATCH, 256, 0, stream>>>(validf, mask, prop, score, out);
}

// Round 7
// 222.646 us; speedup vs baseline: 1.2258x; 1.2258x over previous
//
#include <hip/hip_runtime.h>
#include <stdint.h>

// RPN rotated-NMS post-processor, MI355X. Round 7: r6 + revert diag resolve
// to unrolled 64-step chain (pipelined shuffles) reading from LDS.

#define NBATCH 4
#define AANCH 15
#define HDIM 200
#define WDIM 200
#define MTOT (AANCH*HDIM*WDIM)   // 600000
#define KTOP 1000
#define POSTN 300
#define NBINS 16384
#define CAND_CAP 2048
#define NWORDS 16                // ceil(1000/64)
#define NMS_TH 0.7f
#define BPB 75                   // blocks per batch for hist
#define CHUNK (MTOT/BPB)         // 8000
#define IOU_BPB 125              // iou blocks per batch
#define IOU_WPB 128              // mask words per iou block (8 i-rows x 16)
#define QCAP (IOU_WPB*64)        // 8192: provable max survivors per block
#define TSTR 1025                // transposed-mask LDS row stride

// ---------------- ws layout ----------------
constexpr size_t OFF_HIST = 0;
constexpr size_t SZ_HIST  = (size_t)NBATCH*NBINS*4;                 // 262144
constexpr size_t OFF_CNT  = OFF_HIST + SZ_HIST;
constexpr size_t OFF_THR  = OFF_CNT + 256;
constexpr size_t OFF_CAND = OFF_THR + 256;
constexpr size_t OFF_PROP = OFF_CAND + (size_t)NBATCH*CAND_CAP*8;
constexpr size_t OFF_SCORE= OFF_PROP + (size_t)NBATCH*KTOP*5*4;
constexpr size_t OFF_CORN = OFF_SCORE+ (size_t)NBATCH*KTOP*4;
constexpr size_t OFF_AREA = OFF_CORN + (size_t)NBATCH*KTOP*8*4;
constexpr size_t OFF_VALID= OFF_AREA + (size_t)NBATCH*KTOP*4;
constexpr size_t OFF_XYR  = OFF_VALID+ (size_t)NBATCH*KTOP*4;
constexpr size_t OFF_MASK = OFF_XYR  + (size_t)NBATCH*KTOP*16;
constexpr size_t SZ_MASK  = (size_t)NBATCH*KTOP*NWORDS*8;           // 512000

__device__ __forceinline__ float sigmoid_ref(float x) {
  return 1.0f / (1.0f + expf(-x));
}

// ---------------- histogram: LDS-privatized ----------------
__global__ __launch_bounds__(256) void k_hist(const float* __restrict__ obj,
                                              uint32_t* __restrict__ hist) {
  __shared__ uint32_t h[NBINS];
  for (int i = threadIdx.x; i < NBINS; i += 256) h[i] = 0;
  __syncthreads();
  int n = blockIdx.x / BPB, c = blockIdx.x % BPB;
  const float4* p = (const float4*)(obj + (size_t)n*MTOT + (size_t)c*CHUNK);
  const int nq = CHUNK/4;
  for (int q = threadIdx.x; q < nq; q += 256) {
    float4 v = p[q];
    #pragma unroll
    for (int k = 0; k < 4; ++k) {
      float x = (&v.x)[k];
      uint32_t bits = __float_as_uint(sigmoid_ref(x));
      uint32_t bin = bits >> 16; if (bin > NBINS-1) bin = NBINS-1;
      atomicAdd(&h[bin], 1u);
    }
  }
  __syncthreads();
  for (int i = threadIdx.x; i < NBINS; i += 256) {
    uint32_t v = h[i];
    if (v) atomicAdd(&hist[n*NBINS + i], v);
  }
}

// ---------------- threshold ----------------
__global__ __launch_bounds__(256) void k_thresh(const uint32_t* __restrict__ hist,
                                                uint32_t* __restrict__ thr) {
  __shared__ uint32_t ps[256];
  int n = blockIdx.x, tid = threadIdx.x;
  uint32_t s = 0;
  const uint32_t* hb = &hist[n*NBINS];
  #pragma unroll 4
  for (int b = tid*64; b < tid*64+64; ++b) s += hb[b];
  ps[tid] = s;
  __syncthreads();
  if (tid == 0) {
    uint32_t cum = 0; int cidx = -1;
    for (int cc = 255; cc >= 0; --cc) {
      if (cum + ps[cc] >= KTOP) { cidx = cc; break; }
      cum += ps[cc];
    }
    if (cidx < 0) { thr[n] = 0u; return; }
    int b = cidx*64+63;
    for (; b >= cidx*64; --b) { cum += hb[b]; if (cum >= KTOP) break; }
    thr[n] = (uint32_t)(b < 0 ? 0 : b);
  }
}

// ---------------- compact candidates (wave-aggregated atomics) ----------------
__global__ __launch_bounds__(256) void k_compact(const float* __restrict__ obj,
                                                 const uint32_t* __restrict__ thr,
                                                 uint64_t* __restrict__ cand,
                                                 uint32_t* __restrict__ cnt) {
  int t = blockIdx.x*blockDim.x + threadIdx.x;
  if (t >= NBATCH*MTOT) return;
  int n = t / MTOT;           // wave-uniform: MTOT % 64 == 0
  int rem = t % MTOT;
  int lane = threadIdx.x & 63;
  float x = obj[t];
  uint32_t bits = __float_as_uint(sigmoid_ref(x));
  uint32_t bin = bits >> 16; if (bin > NBINS-1) bin = NBINS-1;
  bool hit = (bin >= thr[n]);
  unsigned long long bal = __ballot(hit);
  if (!bal) return;
  int tot = __popcll(bal);
  int leader = __ffsll(bal) - 1;
  uint32_t base = 0;
  if (lane == leader) base = atomicAdd(&cnt[n], (uint32_t)tot);
  base = __shfl(base, leader);
  if (hit) {
    uint32_t p = base + (uint32_t)__popcll(bal & ((1ull << lane) - 1ull));
    if (p < CAND_CAP) {
      int hw = rem % (HDIM*WDIM);
      int a  = rem / (HDIM*WDIM);
      uint32_t fidx = (uint32_t)(hw*AANCH + a);
      cand[(size_t)n*CAND_CAP + p] = ((uint64_t)bits << 32) | (uint32_t)(~fidx);
    }
  }
}

// ---------------- bitonic sort (2048) + fused decode epilogue ----------------
__global__ __launch_bounds__(1024) void k_sortdec(const uint64_t* __restrict__ cand,
                                                  const uint32_t* __restrict__ cnt,
                                                  const float* __restrict__ breg,
                                                  const float* __restrict__ anch,
                                                  float* __restrict__ prop,
                                                  float* __restrict__ score,
                                                  float* __restrict__ corn,
                                                  float* __restrict__ area,
                                                  float4* __restrict__ xyr,
                                                  uint32_t* __restrict__ validf) {
  __shared__ uint64_t sk[CAND_CAP];
  int n = blockIdx.x, tid = threadIdx.x;
  uint32_t c = cnt[n]; if (c > CAND_CAP) c = CAND_CAP;
  #pragma unroll
  for (int i = tid; i < CAND_CAP; i += 1024)
    sk[i] = (i < (int)c) ? cand[(size_t)n*CAND_CAP + i] : 0ull;
  __syncthreads();
  for (int len = 2; len <= CAND_CAP; len <<= 1) {
    for (int str = len >> 1; str > 0; str >>= 1) {
      #pragma unroll
      for (int i = tid; i < CAND_CAP; i += 1024) {
        int j = i ^ str;
        if (j > i) {
          bool up = ((i & len) == 0);
          uint64_t x = sk[i], y = sk[j];
          if ((x > y) == up) { sk[i] = y; sk[j] = x; }
        }
      }
      __syncthreads();
    }
  }
  // ---- decode entry `tid` (rank tid, descending) ----
  if (tid < KTOP) {
#pragma clang fp contract(off)
    int t = n*KTOP + tid;
    uint64_t key = sk[CAND_CAP-1-tid];
    uint32_t idx = ~(uint32_t)(key & 0xFFFFFFFFull);
    float s = __uint_as_float((uint32_t)(key >> 32));
    int a = idx % AANCH, pos = idx / AANCH;
    int w = pos % WDIM, h = pos / WDIM;
    float d[5], an[5];
    #pragma unroll
    for (int j = 0; j < 5; ++j)
      d[j] = breg[((n*(AANCH*5) + (a*5+j))*HDIM + h)*WDIM + w];
    #pragma unroll
    for (int j = 0; j < 5; ++j)
      an[j] = anch[((size_t)n*MTOT + idx)*5 + j];
    const float CLIP = 4.135166556742356f;           // log(1000/16)
    float dw = fminf(d[2], CLIP), dh = fminf(d[3], CLIP);
    float x  = d[0]*an[2] + an[0];
    float y  = d[1]*an[3] + an[1];
    float bw = expf(dw)*an[2];
    float bh = expf(dh)*an[3];
    float th = an[4] + d[4]*57.29577951308232f;      // 180/pi
    prop[t*5+0]=x; prop[t*5+1]=y; prop[t*5+2]=bw; prop[t*5+3]=bh; prop[t*5+4]=th;
    score[t] = s;
    validf[t] = (bw >= 4.0f && bh >= 4.0f) ? 1u : 0u;
    area[t] = bw*bh;
    float r = 0.5f*sqrtf(bw*bw + bh*bh);
    xyr[t] = make_float4(x, y, r, 0.0f);
    float ang = th * 0.017453292519943295f;          // pi/180
    float cs = cosf(ang), sn = sinf(ang);
    float hw2 = bw*0.5f, hh2 = bh*0.5f;
    const float sx[4] = {1.f,-1.f,-1.f,1.f};
    const float sy[4] = {1.f,1.f,-1.f,-1.f};
    #pragma unroll
    for (int k = 0; k < 4; ++k) {
      float dxk = sx[k]*hw2, dyk = sy[k]*hh2;
      float cx = (x + cs*dxk) - sn*dyk;
      float cy = (y + sn*dxk) + cs*dyk;
      corn[t*8 + k*2 + 0] = cx;
      corn[t*8 + k*2 + 1] = cy;
    }
  }
}

// ---------------- Sutherland-Hodgman (mirrors reference arithmetic) ----------------
__device__ float quad_inter_area(const float* __restrict__ ca, const float* __restrict__ cb) {
#pragma clang fp contract(off)
  float px[8], py[8];
  int n = 4;
  #pragma unroll
  for (int i = 0; i < 4; ++i) { px[i] = ca[2*i]; py[i] = ca[2*i+1]; }
  for (int e = 0; e < 4; ++e) {
    float p1x = cb[2*e], p1y = cb[2*e+1];
    int e2 = (e+1)&3;
    float dx = cb[2*e2] - p1x, dy = cb[2*e2+1] - p1y;
    float sd[8];
    for (int i = 0; i < n; ++i)
      sd[i] = dx*(py[i]-p1y) - dy*(px[i]-p1x);
    float qx[8], qy[8];
    int m = 0;
    for (int i = 0; i < n; ++i) {
      int nx = (i+1 < n) ? i+1 : 0;
      bool ini = sd[i] >= 0.0f, inn = sd[nx] >= 0.0f;
      if (ini) { qx[m]=px[i]; qy[m]=py[i]; ++m; }
      if (ini != inn) {
        float den = sd[i]-sd[nx];
        float dd = (fabsf(den) < 1e-12f) ? 1e-12f : den;
        float tt = sd[i]/dd;
        qx[m] = px[i] + tt*(px[nx]-px[i]);
        qy[m] = py[i] + tt*(py[nx]-py[i]);
        ++m;
      }
    }
    n = m;
    for (int i = 0; i < n; ++i) { px[i]=qx[i]; py[i]=qy[i]; }
    if (n == 0) break;
  }
  float ssum = 0.0f;
  for (int i = 0; i < n; ++i) {
    int nx = (i+1 < n) ? i+1 : 0;
    ssum += px[i]*py[nx] - px[nx]*py[i];
  }
  return 0.5f*fabsf(ssum);
}

// ---------------- fused circle-test + clip; block owns 8 mask rows in LDS ----------------
__global__ __launch_bounds__(256) void k_iou(const float4* __restrict__ xyr,
                                             const float* __restrict__ corn,
                                             const float* __restrict__ area,
                                             uint64_t* __restrict__ mask) {
  __shared__ uint32_t q[QCAP];            // 32 KB
  __shared__ uint32_t qcnt;
  __shared__ uint32_t mrow32[IOU_WPB*2];  // 8 rows x 16 words, as 32-bit halves
  __shared__ float ca8[64];               // 8 rows' corners
  __shared__ float aa8[8];
  int n = blockIdx.x / IOU_BPB;
  int wbase = (blockIdx.x % IOU_BPB) * IOU_WPB;
  int i0 = wbase >> 4;                    // first owned i-row
  int wv = threadIdx.x >> 6, lane = threadIdx.x & 63;
  if (threadIdx.x == 0) qcnt = 0;
  if (threadIdx.x < IOU_WPB*2) mrow32[threadIdx.x] = 0;
  if (threadIdx.x < 64) ca8[threadIdx.x] = corn[(size_t)(n*KTOP + i0)*8 + threadIdx.x];
  if (threadIdx.x >= 64 && threadIdx.x < 72) aa8[threadIdx.x-64] = area[n*KTOP + i0 + threadIdx.x-64];
  __syncthreads();
  for (int w = wv; w < IOU_WPB; w += 4) {
    int word = wbase + w;
    int i = word >> 4;               // word / NWORDS
    int jb = word & 15;              // word % NWORDS
    if (jb*64 + 63 <= i) continue;   // no j > i in this word
    int j = jb*64 + lane;
    bool hit = false;
    if (j > i && j < KTOP) {
      float4 a = xyr[n*KTOP + i];    // wave-uniform
      float4 b = xyr[n*KTOP + j];    // coalesced 16B/lane
      float dx = a.x - b.x, dy = a.y - b.y;
      float rs = a.z + b.z;
      hit = (dx*dx + dy*dy) <= rs*rs*1.0001f;
    }
    unsigned long long bal = __ballot(hit);
    if (!bal) continue;
    int tot = __popcll(bal);
    int leader = __ffsll(bal) - 1;
    uint32_t base = 0;
    if (lane == leader) base = atomicAdd(&qcnt, (uint32_t)tot);
    base = __shfl(base, leader);
    if (hit) {
      int pos = __popcll(bal & ((1ull << lane) - 1ull));
      q[base + pos] = ((uint32_t)i << 10) | (uint32_t)j;
    }
  }
  __syncthreads();
  uint32_t cnt = qcnt;
  for (uint32_t t = threadIdx.x; t < cnt; t += 256) {
    uint32_t code = q[t];
    int i = code >> 10, j = code & 1023;
    int bj = n*KTOP + j;
    float inter = quad_inter_area(&ca8[(i - i0)*8], &corn[(size_t)bj*8]);
    float uni = (aa8[i - i0] + area[bj]) - inter;
    if (inter / fmaxf(uni, 1e-8f) > NMS_TH)
      atomicOr(&mrow32[((i - i0)*NWORDS + (j >> 6))*2 + ((j >> 5) & 1)],
               1u << (j & 31));
  }
  __syncthreads();
  // store the block's 128 contiguous mask words (full overwrite, no atomics)
  uint64_t* dst = &mask[(size_t)n*KTOP*NWORDS + wbase];
  for (int t = threadIdx.x; t < IOU_WPB; t += 256)
    dst[t] = (uint64_t)mrow32[t*2] | ((uint64_t)mrow32[t*2+1] << 32);
}

// ---------------- blocked greedy NMS, LDS-resident, unrolled diag chain ----------------
__global__ __launch_bounds__(256) void k_nms(const uint32_t* __restrict__ validf,
                                             const uint64_t* __restrict__ mask,
                                             const float* __restrict__ prop,
                                             const float* __restrict__ score,
                                             float* __restrict__ out) {
  __shared__ uint64_t smT[NWORDS*TSTR];   // 131200 B, transposed [word][row]
  __shared__ uint64_t kw[NWORDS];
  int n = blockIdx.x;
  int tid = threadIdx.x, wv = tid >> 6, lane = tid & 63;
  const uint64_t* M = &mask[(size_t)n*KTOP*NWORDS];
  // stage transposed: coalesced global reads, conflict-free LDS writes
  for (int g = tid; g < KTOP*NWORDS; g += 256) {
    int row = g >> 4, l = g & 15;
    smT[l*TSTR + row] = M[g];
  }
  if (wv == 0) {
    #pragma unroll
    for (int w = 0; w < NWORDS; ++w) {
      int k = w*64 + lane;
      uint32_t v = (k < KTOP) ? validf[n*KTOP + k] : 0u;
      unsigned long long b = __ballot(v != 0u);
      if (lane == 0) kw[w] = (uint64_t)b;
    }
  }
  __syncthreads();

  for (int b = 0; b < NWORDS; ++b) {
    // --- diagonal resolve (wave 0): unrolled, shuffles independent of chain ---
    if (wv == 0) {
      int row = b*64 + lane;
      uint64_t diag = (row < KTOP) ? smT[b*TSTR + row] : 0ull;
      uint64_t alive = kw[b];
      #pragma unroll
      for (int i = 0; i < 64; ++i) {
        uint64_t d = __shfl(diag, i);         // bits strictly > i
        alive &= ~(((alive >> i) & 1ull) ? d : 0ull);
      }
      if (lane == 0) kw[b] = alive;
    }
    __syncthreads();
    if (b == NWORDS-1) break;
    uint64_t alive = kw[b];
    // --- cross-block apply: words l in (b, NWORDS), 4 waves round-robin ---
    int row = b*64 + lane;
    bool me = ((alive >> lane) & 1ull) && (row < KTOP);
    uint64_t mv0=0, mv1=0, mv2=0, mv3=0;
    int l0 = b+1+wv, l1 = l0+4, l2 = l0+8, l3 = l0+12;
    if (me) {
      if (l0 < NWORDS) mv0 = smT[l0*TSTR + row];
      if (l1 < NWORDS) mv1 = smT[l1*TSTR + row];
      if (l2 < NWORDS) mv2 = smT[l2*TSTR + row];
      if (l3 < NWORDS) mv3 = smT[l3*TSTR + row];
    }
    #pragma unroll
    for (int s = 1; s < 64; s <<= 1) {
      mv0 |= __shfl_xor(mv0, s);
      mv1 |= __shfl_xor(mv1, s);
      mv2 |= __shfl_xor(mv2, s);
      mv3 |= __shfl_xor(mv3, s);
    }
    if (lane == 0) {
      if (l0 < NWORDS) kw[l0] &= ~mv0;
      if (l1 < NWORDS) kw[l1] &= ~mv1;
      if (l2 < NWORDS) kw[l2] &= ~mv2;
      if (l3 < NWORDS) kw[l3] &= ~mv3;
    }
    __syncthreads();
  }

  // rank <= POSTN trim (thread 0), then all threads write output
  if (tid == 0) {
    int prev = 0;
    #pragma unroll
    for (int t = 0; t < NWORDS; ++t) {
      uint64_t wrd = kw[t];
      int pc = __popcll(wrd);
      if (prev >= POSTN) wrd = 0;
      else if (prev + pc > POSTN) {
        int allow = POSTN - prev;
        while (__popcll(wrd) > allow) wrd &= ~(1ull << (63 - __clzll(wrd)));
      }
      prev += __popcll(wrd);
      kw[t] = wrd;
    }
  }
  __syncthreads();
  for (int k = tid; k < KTOP; k += 256) {
    bool bb = (kw[k>>6] >> (k&63)) & 1ull;
    float f = bb ? 1.0f : 0.0f;
    int t = n*KTOP + k;
    #pragma unroll
    for (int c = 0; c < 5; ++c) out[t*6 + c] = prop[t*5 + c] * f;
    out[t*6 + 5] = score[t] * f;
  }
}

extern "C" void kernel_launch(void* const* d_in, const int* in_sizes, int n_in,
                              void* d_out, int out_size, void* d_ws, size_t ws_size,
                              hipStream_t stream) {
  const float* obj  = (const float*)d_in[0];
  const float* breg = (const float*)d_in[1];
  const float* anch = (const float*)d_in[2];
  float* out = (float*)d_out;
  char* ws = (char*)d_ws;

  uint32_t* hist  = (uint32_t*)(ws + OFF_HIST);
  uint32_t* cnt   = (uint32_t*)(ws + OFF_CNT);
  uint32_t* thr   = (uint32_t*)(ws + OFF_THR);
  uint64_t* cand  = (uint64_t*)(ws + OFF_CAND);
  float*    prop  = (float*)(ws + OFF_PROP);
  float*    score = (float*)(ws + OFF_SCORE);
  float*    corn  = (float*)(ws + OFF_CORN);
  float*    area  = (float*)(ws + OFF_AREA);
  uint32_t* validf= (uint32_t*)(ws + OFF_VALID);
  float4*   xyr   = (float4*)(ws + OFF_XYR);
  uint64_t* mask  = (uint64_t*)(ws + OFF_MASK);

  hipMemsetAsync(ws, 0, OFF_CAND, stream);   // hist + cnt + thr

  int nt = NBATCH*MTOT;
  k_hist   <<<NBATCH*BPB, 256, 0, stream>>>(obj, hist);
  k_thresh <<<NBATCH, 256, 0, stream>>>(hist, thr);
  k_compact<<<(nt+255)/256, 256, 0, stream>>>(obj, thr, cand, cnt);
  k_sortdec<<<NBATCH, 1024, 0, stream>>>(cand, cnt, breg, anch, prop, score, corn, area, xyr, validf);
  k_iou    <<<NBATCH*IOU_BPB, 256, 0, stream>>>(xyr, corn, area, mask);
  k_nms    <<<NBATCH, 256, 0, stream>>>(validf, mask, prop, score, out);
}

// Round 8
// 200.939 us; speedup vs baseline: 1.3582x; 1.1080x over previous
//
#include <hip/hip_runtime.h>
#include <stdint.h>

// RPN rotated-NMS post-processor, MI355X. Round 8: NMS without LDS staging —
// transposed global mask (written by k_iou), readlane/SALU diag resolve,
// register double-buffered cross-apply prefetch.

#define NBATCH 4
#define AANCH 15
#define HDIM 200
#define WDIM 200
#define MTOT (AANCH*HDIM*WDIM)   // 600000
#define KTOP 1000
#define POSTN 300
#define NBINS 16384
#define CAND_CAP 2048
#define NWORDS 16                // ceil(1000/64)
#define NMS_TH 0.7f
#define BPB 75                   // blocks per batch for hist
#define CHUNK (MTOT/BPB)         // 8000
#define IOU_BPB 125              // iou blocks per batch
#define IOU_WPB 128              // mask words per iou block (8 i-rows x 16)
#define QCAP (IOU_WPB*64)        // 8192: provable max survivors per block

// ---------------- ws layout ----------------
constexpr size_t OFF_HIST = 0;
constexpr size_t SZ_HIST  = (size_t)NBATCH*NBINS*4;                 // 262144
constexpr size_t OFF_CNT  = OFF_HIST + SZ_HIST;
constexpr size_t OFF_THR  = OFF_CNT + 256;
constexpr size_t OFF_CAND = OFF_THR + 256;
constexpr size_t OFF_PROP = OFF_CAND + (size_t)NBATCH*CAND_CAP*8;
constexpr size_t OFF_SCORE= OFF_PROP + (size_t)NBATCH*KTOP*5*4;
constexpr size_t OFF_CORN = OFF_SCORE+ (size_t)NBATCH*KTOP*4;
constexpr size_t OFF_AREA = OFF_CORN + (size_t)NBATCH*KTOP*8*4;
constexpr size_t OFF_VALID= OFF_AREA + (size_t)NBATCH*KTOP*4;
constexpr size_t OFF_XYR  = OFF_VALID+ (size_t)NBATCH*KTOP*4;
constexpr size_t OFF_MASK = OFF_XYR  + (size_t)NBATCH*KTOP*16;      // maskT [n][l][row]

__device__ __forceinline__ float sigmoid_ref(float x) {
  return 1.0f / (1.0f + expf(-x));
}

// ---------------- histogram: LDS-privatized ----------------
__global__ __launch_bounds__(256) void k_hist(const float* __restrict__ obj,
                                              uint32_t* __restrict__ hist) {
  __shared__ uint32_t h[NBINS];
  for (int i = threadIdx.x; i < NBINS; i += 256) h[i] = 0;
  __syncthreads();
  int n = blockIdx.x / BPB, c = blockIdx.x % BPB;
  const float4* p = (const float4*)(obj + (size_t)n*MTOT + (size_t)c*CHUNK);
  const int nq = CHUNK/4;
  for (int q = threadIdx.x; q < nq; q += 256) {
    float4 v = p[q];
    #pragma unroll
    for (int k = 0; k < 4; ++k) {
      float x = (&v.x)[k];
      uint32_t bits = __float_as_uint(sigmoid_ref(x));
      uint32_t bin = bits >> 16; if (bin > NBINS-1) bin = NBINS-1;
      atomicAdd(&h[bin], 1u);
    }
  }
  __syncthreads();
  for (int i = threadIdx.x; i < NBINS; i += 256) {
    uint32_t v = h[i];
    if (v) atomicAdd(&hist[n*NBINS + i], v);
  }
}

// ---------------- threshold ----------------
__global__ __launch_bounds__(256) void k_thresh(const uint32_t* __restrict__ hist,
                                                uint32_t* __restrict__ thr) {
  __shared__ uint32_t ps[256];
  int n = blockIdx.x, tid = threadIdx.x;
  uint32_t s = 0;
  const uint32_t* hb = &hist[n*NBINS];
  #pragma unroll 4
  for (int b = tid*64; b < tid*64+64; ++b) s += hb[b];
  ps[tid] = s;
  __syncthreads();
  if (tid == 0) {
    uint32_t cum = 0; int cidx = -1;
    for (int cc = 255; cc >= 0; --cc) {
      if (cum + ps[cc] >= KTOP) { cidx = cc; break; }
      cum += ps[cc];
    }
    if (cidx < 0) { thr[n] = 0u; return; }
    int b = cidx*64+63;
    for (; b >= cidx*64; --b) { cum += hb[b]; if (cum >= KTOP) break; }
    thr[n] = (uint32_t)(b < 0 ? 0 : b);
  }
}

// ---------------- compact candidates (wave-aggregated atomics) ----------------
__global__ __launch_bounds__(256) void k_compact(const float* __restrict__ obj,
                                                 const uint32_t* __restrict__ thr,
                                                 uint64_t* __restrict__ cand,
                                                 uint32_t* __restrict__ cnt) {
  int t = blockIdx.x*blockDim.x + threadIdx.x;
  if (t >= NBATCH*MTOT) return;
  int n = t / MTOT;           // wave-uniform: MTOT % 64 == 0
  int rem = t % MTOT;
  int lane = threadIdx.x & 63;
  float x = obj[t];
  uint32_t bits = __float_as_uint(sigmoid_ref(x));
  uint32_t bin = bits >> 16; if (bin > NBINS-1) bin = NBINS-1;
  bool hit = (bin >= thr[n]);
  unsigned long long bal = __ballot(hit);
  if (!bal) return;
  int tot = __popcll(bal);
  int leader = __ffsll(bal) - 1;
  uint32_t base = 0;
  if (lane == leader) base = atomicAdd(&cnt[n], (uint32_t)tot);
  base = __shfl(base, leader);
  if (hit) {
    uint32_t p = base + (uint32_t)__popcll(bal & ((1ull << lane) - 1ull));
    if (p < CAND_CAP) {
      int hw = rem % (HDIM*WDIM);
      int a  = rem / (HDIM*WDIM);
      uint32_t fidx = (uint32_t)(hw*AANCH + a);
      cand[(size_t)n*CAND_CAP + p] = ((uint64_t)bits << 32) | (uint32_t)(~fidx);
    }
  }
}

// ---------------- bitonic sort (2048) + fused decode epilogue ----------------
__global__ __launch_bounds__(1024) void k_sortdec(const uint64_t* __restrict__ cand,
                                                  const uint32_t* __restrict__ cnt,
                                                  const float* __restrict__ breg,
                                                  const float* __restrict__ anch,
                                                  float* __restrict__ prop,
                                                  float* __restrict__ score,
                                                  float* __restrict__ corn,
                                                  float* __restrict__ area,
                                                  float4* __restrict__ xyr,
                                                  uint32_t* __restrict__ validf) {
  __shared__ uint64_t sk[CAND_CAP];
  int n = blockIdx.x, tid = threadIdx.x;
  uint32_t c = cnt[n]; if (c > CAND_CAP) c = CAND_CAP;
  #pragma unroll
  for (int i = tid; i < CAND_CAP; i += 1024)
    sk[i] = (i < (int)c) ? cand[(size_t)n*CAND_CAP + i] : 0ull;
  __syncthreads();
  for (int len = 2; len <= CAND_CAP; len <<= 1) {
    for (int str = len >> 1; str > 0; str >>= 1) {
      #pragma unroll
      for (int i = tid; i < CAND_CAP; i += 1024) {
        int j = i ^ str;
        if (j > i) {
          bool up = ((i & len) == 0);
          uint64_t x = sk[i], y = sk[j];
          if ((x > y) == up) { sk[i] = y; sk[j] = x; }
        }
      }
      __syncthreads();
    }
  }
  // ---- decode entry `tid` (rank tid, descending) ----
  if (tid < KTOP) {
#pragma clang fp contract(off)
    int t = n*KTOP + tid;
    uint64_t key = sk[CAND_CAP-1-tid];
    uint32_t idx = ~(uint32_t)(key & 0xFFFFFFFFull);
    float s = __uint_as_float((uint32_t)(key >> 32));
    int a = idx % AANCH, pos = idx / AANCH;
    int w = pos % WDIM, h = pos / WDIM;
    float d[5], an[5];
    #pragma unroll
    for (int j = 0; j < 5; ++j)
      d[j] = breg[((n*(AANCH*5) + (a*5+j))*HDIM + h)*WDIM + w];
    #pragma unroll
    for (int j = 0; j < 5; ++j)
      an[j] = anch[((size_t)n*MTOT + idx)*5 + j];
    const float CLIP = 4.135166556742356f;           // log(1000/16)
    float dw = fminf(d[2], CLIP), dh = fminf(d[3], CLIP);
    float x  = d[0]*an[2] + an[0];
    float y  = d[1]*an[3] + an[1];
    float bw = expf(dw)*an[2];
    float bh = expf(dh)*an[3];
    float th = an[4] + d[4]*57.29577951308232f;      // 180/pi
    prop[t*5+0]=x; prop[t*5+1]=y; prop[t*5+2]=bw; prop[t*5+3]=bh; prop[t*5+4]=th;
    score[t] = s;
    validf[t] = (bw >= 4.0f && bh >= 4.0f) ? 1u : 0u;
    area[t] = bw*bh;
    float r = 0.5f*sqrtf(bw*bw + bh*bh);
    xyr[t] = make_float4(x, y, r, 0.0f);
    float ang = th * 0.017453292519943295f;          // pi/180
    float cs = cosf(ang), sn = sinf(ang);
    float hw2 = bw*0.5f, hh2 = bh*0.5f;
    const float sx[4] = {1.f,-1.f,-1.f,1.f};
    const float sy[4] = {1.f,1.f,-1.f,-1.f};
    #pragma unroll
    for (int k = 0; k < 4; ++k) {
      float dxk = sx[k]*hw2, dyk = sy[k]*hh2;
      float cx = (x + cs*dxk) - sn*dyk;
      float cy = (y + sn*dxk) + cs*dyk;
      corn[t*8 + k*2 + 0] = cx;
      corn[t*8 + k*2 + 1] = cy;
    }
  }
}

// ---------------- Sutherland-Hodgman (mirrors reference arithmetic) ----------------
__device__ float quad_inter_area(const float* __restrict__ ca, const float* __restrict__ cb) {
#pragma clang fp contract(off)
  float px[8], py[8];
  int n = 4;
  #pragma unroll
  for (int i = 0; i < 4; ++i) { px[i] = ca[2*i]; py[i] = ca[2*i+1]; }
  for (int e = 0; e < 4; ++e) {
    float p1x = cb[2*e], p1y = cb[2*e+1];
    int e2 = (e+1)&3;
    float dx = cb[2*e2] - p1x, dy = cb[2*e2+1] - p1y;
    float sd[8];
    for (int i = 0; i < n; ++i)
      sd[i] = dx*(py[i]-p1y) - dy*(px[i]-p1x);
    float qx[8], qy[8];
    int m = 0;
    for (int i = 0; i < n; ++i) {
      int nx = (i+1 < n) ? i+1 : 0;
      bool ini = sd[i] >= 0.0f, inn = sd[nx] >= 0.0f;
      if (ini) { qx[m]=px[i]; qy[m]=py[i]; ++m; }
      if (ini != inn) {
        float den = sd[i]-sd[nx];
        float dd = (fabsf(den) < 1e-12f) ? 1e-12f : den;
        float tt = sd[i]/dd;
        qx[m] = px[i] + tt*(px[nx]-px[i]);
        qy[m] = py[i] + tt*(py[nx]-py[i]);
        ++m;
      }
    }
    n = m;
    for (int i = 0; i < n; ++i) { px[i]=qx[i]; py[i]=qy[i]; }
    if (n == 0) break;
  }
  float ssum = 0.0f;
  for (int i = 0; i < n; ++i) {
    int nx = (i+1 < n) ? i+1 : 0;
    ssum += px[i]*py[nx] - px[nx]*py[i];
  }
  return 0.5f*fabsf(ssum);
}

// ---------------- fused circle-test + clip; writes TRANSPOSED mask ----------------
__global__ __launch_bounds__(256) void k_iou(const float4* __restrict__ xyr,
                                             const float* __restrict__ corn,
                                             const float* __restrict__ area,
                                             uint64_t* __restrict__ maskT) {
  __shared__ uint32_t q[QCAP];            // 32 KB
  __shared__ uint32_t qcnt;
  __shared__ uint32_t mrow32[IOU_WPB*2];  // 8 rows x 16 words, as 32-bit halves
  __shared__ float ca8[64];               // 8 rows' corners
  __shared__ float aa8[8];
  int n = blockIdx.x / IOU_BPB;
  int wbase = (blockIdx.x % IOU_BPB) * IOU_WPB;
  int i0 = wbase >> 4;                    // first owned i-row
  int wv = threadIdx.x >> 6, lane = threadIdx.x & 63;
  if (threadIdx.x == 0) qcnt = 0;
  if (threadIdx.x < IOU_WPB*2) mrow32[threadIdx.x] = 0;
  if (threadIdx.x < 64) ca8[threadIdx.x] = corn[(size_t)(n*KTOP + i0)*8 + threadIdx.x];
  if (threadIdx.x >= 64 && threadIdx.x < 72) aa8[threadIdx.x-64] = area[n*KTOP + i0 + threadIdx.x-64];
  __syncthreads();
  for (int w = wv; w < IOU_WPB; w += 4) {
    int word = wbase + w;
    int i = word >> 4;               // word / NWORDS
    int jb = word & 15;              // word % NWORDS
    if (jb*64 + 63 <= i) continue;   // no j > i in this word
    int j = jb*64 + lane;
    bool hit = false;
    if (j > i && j < KTOP) {
      float4 a = xyr[n*KTOP + i];    // wave-uniform
      float4 b = xyr[n*KTOP + j];    // coalesced 16B/lane
      float dx = a.x - b.x, dy = a.y - b.y;
      float rs = a.z + b.z;
      hit = (dx*dx + dy*dy) <= rs*rs*1.0001f;
    }
    unsigned long long bal = __ballot(hit);
    if (!bal) continue;
    int tot = __popcll(bal);
    int leader = __ffsll(bal) - 1;
    uint32_t base = 0;
    if (lane == leader) base = atomicAdd(&qcnt, (uint32_t)tot);
    base = __shfl(base, leader);
    if (hit) {
      int pos = __popcll(bal & ((1ull << lane) - 1ull));
      q[base + pos] = ((uint32_t)i << 10) | (uint32_t)j;
    }
  }
  __syncthreads();
  uint32_t cnt = qcnt;
  for (uint32_t t = threadIdx.x; t < cnt; t += 256) {
    uint32_t code = q[t];
    int i = code >> 10, j = code & 1023;
    int bj = n*KTOP + j;
    float inter = quad_inter_area(&ca8[(i - i0)*8], &corn[(size_t)bj*8]);
    float uni = (aa8[i - i0] + area[bj]) - inter;
    if (inter / fmaxf(uni, 1e-8f) > NMS_TH)
      atomicOr(&mrow32[((i - i0)*NWORDS + (j >> 6))*2 + ((j >> 5) & 1)],
               1u << (j & 31));
  }
  __syncthreads();
  // store transposed: maskT[n][l][row] (disjoint cells, full overwrite)
  uint64_t* dstT = &maskT[(size_t)n*NWORDS*KTOP];
  for (int t = threadIdx.x; t < IOU_WPB; t += 256) {
    int r = t >> 4, l = t & 15;
    dstT[(size_t)l*KTOP + i0 + r] =
      (uint64_t)mrow32[(r*NWORDS + l)*2] | ((uint64_t)mrow32[(r*NWORDS + l)*2 + 1] << 32);
  }
}

// ---------------- blocked greedy NMS: no staging, readlane diag, prefetch ----------------
__global__ __launch_bounds__(256) void k_nms(const uint32_t* __restrict__ validf,
                                             const uint64_t* __restrict__ maskT,
                                             const float* __restrict__ prop,
                                             const float* __restrict__ score,
                                             float* __restrict__ out) {
  __shared__ uint64_t kw[NWORDS];
  int n = blockIdx.x;
  int tid = threadIdx.x, wv = tid >> 6, lane = tid & 63;
  const uint64_t* MT = &maskT[(size_t)n*NWORDS*KTOP];

  // wave0: preload all 16 diag words (lane holds row b*64+lane's word b)
  uint64_t dreg[NWORDS];
  if (wv == 0) {
    #pragma unroll
    for (int b = 0; b < NWORDS; ++b) {
      int row = b*64 + lane;
      dreg[b] = MT[(size_t)b*KTOP + (row < KTOP ? row : 0)];
    }
    #pragma unroll
    for (int w = 0; w < NWORDS; ++w) {
      int k = w*64 + lane;
      uint32_t v = (k < KTOP) ? validf[n*KTOP + k] : 0u;
      unsigned long long bm = __ballot(v != 0u);
      if (lane == 0) kw[w] = (uint64_t)bm;
    }
  }
  __syncthreads();

  // cross-apply double buffer: phase b uses rows b*64+lane at words l=b+1+wv+4k
  uint64_t cur0=0, cur1=0, cur2=0, cur3=0;
  {
    int row = lane;            // phase 0 rows
    int l0 = 1 + wv;
    cur0 = (l0    < NWORDS) ? MT[(size_t)(l0   )*KTOP + row] : 0ull;
    cur1 = (l0+4  < NWORDS) ? MT[(size_t)(l0+4 )*KTOP + row] : 0ull;
    cur2 = (l0+8  < NWORDS) ? MT[(size_t)(l0+8 )*KTOP + row] : 0ull;
    cur3 = (l0+12 < NWORDS) ? MT[(size_t)(l0+12)*KTOP + row] : 0ull;
  }

  for (int b = 0; b < NWORDS; ++b) {
    // --- diag resolve (wave 0): readlane + branchless SALU chain, uniform ---
    if (wv == 0) {
      uint64_t alive = kw[b];
      uint32_t dlo = (uint32_t)dreg[b], dhi = (uint32_t)(dreg[b] >> 32);
      #pragma unroll
      for (int i = 0; i < 64; ++i) {
        uint32_t lo = __builtin_amdgcn_readlane(dlo, i);
        uint32_t hi = __builtin_amdgcn_readlane(dhi, i);
        uint64_t d = ((uint64_t)hi << 32) | lo;
        uint64_t m = (uint64_t)0 - ((alive >> i) & 1ull);
        alive &= ~(d & m);
      }
      if (lane == 0) kw[b] = alive;
    }
    // --- prefetch next phase's apply rows (alive-independent) ---
    uint64_t nxt0=0, nxt1=0, nxt2=0, nxt3=0;
    if (b + 2 < NWORDS) {
      int row = (b+1)*64 + lane;     // <= 959, in range
      int l0 = b + 2 + wv;
      nxt0 = (l0    < NWORDS) ? MT[(size_t)(l0   )*KTOP + row] : 0ull;
      nxt1 = (l0+4  < NWORDS) ? MT[(size_t)(l0+4 )*KTOP + row] : 0ull;
      nxt2 = (l0+8  < NWORDS) ? MT[(size_t)(l0+8 )*KTOP + row] : 0ull;
      nxt3 = (l0+12 < NWORDS) ? MT[(size_t)(l0+12)*KTOP + row] : 0ull;
    }
    __syncthreads();
    if (b < NWORDS-1) {
      uint64_t alive = kw[b];
      uint64_t me = (uint64_t)0 - ((alive >> lane) & 1ull);
      uint64_t mv0 = cur0 & me, mv1 = cur1 & me, mv2 = cur2 & me, mv3 = cur3 & me;
      #pragma unroll
      for (int s = 1; s < 64; s <<= 1) {
        mv0 |= __shfl_xor(mv0, s);
        mv1 |= __shfl_xor(mv1, s);
        mv2 |= __shfl_xor(mv2, s);
        mv3 |= __shfl_xor(mv3, s);
      }
      if (lane == 0) {
        int l0 = b + 1 + wv;
        if (l0    < NWORDS) kw[l0   ] &= ~mv0;
        if (l0+4  < NWORDS) kw[l0+4 ] &= ~mv1;
        if (l0+8  < NWORDS) kw[l0+8 ] &= ~mv2;
        if (l0+12 < NWORDS) kw[l0+12] &= ~mv3;
      }
      __syncthreads();
    }
    cur0=nxt0; cur1=nxt1; cur2=nxt2; cur3=nxt3;
  }

  // rank <= POSTN trim (thread 0), then all threads write output
  if (tid == 0) {
    int prev = 0;
    #pragma unroll
    for (int t = 0; t < NWORDS; ++t) {
      uint64_t wrd = kw[t];
      int pc = __popcll(wrd);
      if (prev >= POSTN) wrd = 0;
      else if (prev + pc > POSTN) {
        int allow = POSTN - prev;
        while (__popcll(wrd) > allow) wrd &= ~(1ull << (63 - __clzll(wrd)));
      }
      prev += __popcll(wrd);
      kw[t] = wrd;
    }
  }
  __syncthreads();
  for (int k = tid; k < KTOP; k += 256) {
    bool bb = (kw[k>>6] >> (k&63)) & 1ull;
    float f = bb ? 1.0f : 0.0f;
    int t = n*KTOP + k;
    #pragma unroll
    for (int c = 0; c < 5; ++c) out[t*6 + c] = prop[t*5 + c] * f;
    out[t*6 + 5] = score[t] * f;
  }
}

extern "C" void kernel_launch(void* const* d_in, const int* in_sizes, int n_in,
                              void* d_out, int out_size, void* d_ws, size_t ws_size,
                              hipStream_t stream) {
  const float* obj  = (const float*)d_in[0];
  const float* breg = (const float*)d_in[1];
  const float* anch = (const float*)d_in[2];
  float* out = (float*)d_out;
  char* ws = (char*)d_ws;

  uint32_t* hist  = (uint32_t*)(ws + OFF_HIST);
  uint32_t* cnt   = (uint32_t*)(ws + OFF_CNT);
  uint32_t* thr   = (uint32_t*)(ws + OFF_THR);
  uint64_t* cand  = (uint64_t*)(ws + OFF_CAND);
  float*    prop  = (float*)(ws + OFF_PROP);
  float*    score = (float*)(ws + OFF_SCORE);
  float*    corn  = (float*)(ws + OFF_CORN);
  float*    area  = (float*)(ws + OFF_AREA);
  uint32_t* validf= (uint32_t*)(ws + OFF_VALID);
  float4*   xyr   = (float4*)(ws + OFF_XYR);
  uint64_t* maskT = (uint64_t*)(ws + OFF_MASK);

  hipMemsetAsync(ws, 0, OFF_CAND, stream);   // hist + cnt + thr

  int nt = NBATCH*MTOT;
  k_hist   <<<NBATCH*BPB, 256, 0, stream>>>(obj, hist);
  k_thresh <<<NBATCH, 256, 0, stream>>>(hist, thr);
  k_compact<<<(nt+255)/256, 256, 0, stream>>>(obj, thr, cand, cnt);
  k_sortdec<<<NBATCH, 1024, 0, stream>>>(cand, cnt, breg, anch, prop, score, corn, area, xyr, validf);
  k_iou    <<<NBATCH*IOU_BPB, 256, 0, stream>>>(xyr, corn, area, maskT);
  k_nms    <<<NBATCH, 256, 0, stream>>>(validf, maskT, prop, score, out);
}

// Round 9
// 196.295 us; speedup vs baseline: 1.3904x; 1.0237x over previous
//
#include <hip/hip_runtime.h>
#include <stdint.h>

// RPN rotated-NMS post-processor, MI355X. Round 9: k_iou with LDS-staged xyr
// (scan loop reads LDS not global), 4 rows/block (1000 blocks, 2x occupancy,
// half the serial scan length). Rest unchanged from r8.

#define NBATCH 4
#define AANCH 15
#define HDIM 200
#define WDIM 200
#define MTOT (AANCH*HDIM*WDIM)   // 600000
#define KTOP 1000
#define POSTN 300
#define NBINS 16384
#define CAND_CAP 2048
#define NWORDS 16                // ceil(1000/64)
#define NMS_TH 0.7f
#define BPB 75                   // blocks per batch for hist
#define CHUNK (MTOT/BPB)         // 8000
#define IOU_ROWS 4               // i-rows per iou block
#define IOU_BPB 250              // iou blocks per batch
#define IOU_WPB (IOU_ROWS*NWORDS) // 64 mask words per iou block
#define QCAP 4096                // provable max survivors (4 rows x <=1000 j)

// ---------------- ws layout ----------------
constexpr size_t OFF_HIST = 0;
constexpr size_t SZ_HIST  = (size_t)NBATCH*NBINS*4;                 // 262144
constexpr size_t OFF_CNT  = OFF_HIST + SZ_HIST;
constexpr size_t OFF_THR  = OFF_CNT + 256;
constexpr size_t OFF_CAND = OFF_THR + 256;
constexpr size_t OFF_PROP = OFF_CAND + (size_t)NBATCH*CAND_CAP*8;
constexpr size_t OFF_SCORE= OFF_PROP + (size_t)NBATCH*KTOP*5*4;
constexpr size_t OFF_CORN = OFF_SCORE+ (size_t)NBATCH*KTOP*4;
constexpr size_t OFF_AREA = OFF_CORN + (size_t)NBATCH*KTOP*8*4;
constexpr size_t OFF_VALID= OFF_AREA + (size_t)NBATCH*KTOP*4;
constexpr size_t OFF_XYR  = OFF_VALID+ (size_t)NBATCH*KTOP*4;
constexpr size_t OFF_MASK = OFF_XYR  + (size_t)NBATCH*KTOP*16;      // maskT [n][l][row]

__device__ __forceinline__ float sigmoid_ref(float x) {
  return 1.0f / (1.0f + expf(-x));
}

// ---------------- histogram: LDS-privatized ----------------
__global__ __launch_bounds__(256) void k_hist(const float* __restrict__ obj,
                                              uint32_t* __restrict__ hist) {
  __shared__ uint32_t h[NBINS];
  for (int i = threadIdx.x; i < NBINS; i += 256) h[i] = 0;
  __syncthreads();
  int n = blockIdx.x / BPB, c = blockIdx.x % BPB;
  const float4* p = (const float4*)(obj + (size_t)n*MTOT + (size_t)c*CHUNK);
  const int nq = CHUNK/4;
  for (int q = threadIdx.x; q < nq; q += 256) {
    float4 v = p[q];
    #pragma unroll
    for (int k = 0; k < 4; ++k) {
      float x = (&v.x)[k];
      uint32_t bits = __float_as_uint(sigmoid_ref(x));
      uint32_t bin = bits >> 16; if (bin > NBINS-1) bin = NBINS-1;
      atomicAdd(&h[bin], 1u);
    }
  }
  __syncthreads();
  for (int i = threadIdx.x; i < NBINS; i += 256) {
    uint32_t v = h[i];
    if (v) atomicAdd(&hist[n*NBINS + i], v);
  }
}

// ---------------- threshold ----------------
__global__ __launch_bounds__(256) void k_thresh(const uint32_t* __restrict__ hist,
                                                uint32_t* __restrict__ thr) {
  __shared__ uint32_t ps[256];
  int n = blockIdx.x, tid = threadIdx.x;
  uint32_t s = 0;
  const uint32_t* hb = &hist[n*NBINS];
  #pragma unroll 4
  for (int b = tid*64; b < tid*64+64; ++b) s += hb[b];
  ps[tid] = s;
  __syncthreads();
  if (tid == 0) {
    uint32_t cum = 0; int cidx = -1;
    for (int cc = 255; cc >= 0; --cc) {
      if (cum + ps[cc] >= KTOP) { cidx = cc; break; }
      cum += ps[cc];
    }
    if (cidx < 0) { thr[n] = 0u; return; }
    int b = cidx*64+63;
    for (; b >= cidx*64; --b) { cum += hb[b]; if (cum >= KTOP) break; }
    thr[n] = (uint32_t)(b < 0 ? 0 : b);
  }
}

// ---------------- compact candidates (wave-aggregated atomics) ----------------
__global__ __launch_bounds__(256) void k_compact(const float* __restrict__ obj,
                                                 const uint32_t* __restrict__ thr,
                                                 uint64_t* __restrict__ cand,
                                                 uint32_t* __restrict__ cnt) {
  int t = blockIdx.x*blockDim.x + threadIdx.x;
  if (t >= NBATCH*MTOT) return;
  int n = t / MTOT;           // wave-uniform: MTOT % 64 == 0
  int rem = t % MTOT;
  int lane = threadIdx.x & 63;
  float x = obj[t];
  uint32_t bits = __float_as_uint(sigmoid_ref(x));
  uint32_t bin = bits >> 16; if (bin > NBINS-1) bin = NBINS-1;
  bool hit = (bin >= thr[n]);
  unsigned long long bal = __ballot(hit);
  if (!bal) return;
  int tot = __popcll(bal);
  int leader = __ffsll(bal) - 1;
  uint32_t base = 0;
  if (lane == leader) base = atomicAdd(&cnt[n], (uint32_t)tot);
  base = __shfl(base, leader);
  if (hit) {
    uint32_t p = base + (uint32_t)__popcll(bal & ((1ull << lane) - 1ull));
    if (p < CAND_CAP) {
      int hw = rem % (HDIM*WDIM);
      int a  = rem / (HDIM*WDIM);
      uint32_t fidx = (uint32_t)(hw*AANCH + a);
      cand[(size_t)n*CAND_CAP + p] = ((uint64_t)bits << 32) | (uint32_t)(~fidx);
    }
  }
}

// ---------------- bitonic sort (2048) + fused decode epilogue ----------------
__global__ __launch_bounds__(1024) void k_sortdec(const uint64_t* __restrict__ cand,
                                                  const uint32_t* __restrict__ cnt,
                                                  const float* __restrict__ breg,
                                                  const float* __restrict__ anch,
                                                  float* __restrict__ prop,
                                                  float* __restrict__ score,
                                                  float* __restrict__ corn,
                                                  float* __restrict__ area,
                                                  float4* __restrict__ xyr,
                                                  uint32_t* __restrict__ validf) {
  __shared__ uint64_t sk[CAND_CAP];
  int n = blockIdx.x, tid = threadIdx.x;
  uint32_t c = cnt[n]; if (c > CAND_CAP) c = CAND_CAP;
  #pragma unroll
  for (int i = tid; i < CAND_CAP; i += 1024)
    sk[i] = (i < (int)c) ? cand[(size_t)n*CAND_CAP + i] : 0ull;
  __syncthreads();
  for (int len = 2; len <= CAND_CAP; len <<= 1) {
    for (int str = len >> 1; str > 0; str >>= 1) {
      #pragma unroll
      for (int i = tid; i < CAND_CAP; i += 1024) {
        int j = i ^ str;
        if (j > i) {
          bool up = ((i & len) == 0);
          uint64_t x = sk[i], y = sk[j];
          if ((x > y) == up) { sk[i] = y; sk[j] = x; }
        }
      }
      __syncthreads();
    }
  }
  // ---- decode entry `tid` (rank tid, descending) ----
  if (tid < KTOP) {
#pragma clang fp contract(off)
    int t = n*KTOP + tid;
    uint64_t key = sk[CAND_CAP-1-tid];
    uint32_t idx = ~(uint32_t)(key & 0xFFFFFFFFull);
    float s = __uint_as_float((uint32_t)(key >> 32));
    int a = idx % AANCH, pos = idx / AANCH;
    int w = pos % WDIM, h = pos / WDIM;
    float d[5], an[5];
    #pragma unroll
    for (int j = 0; j < 5; ++j)
      d[j] = breg[((n*(AANCH*5) + (a*5+j))*HDIM + h)*WDIM + w];
    #pragma unroll
    for (int j = 0; j < 5; ++j)
      an[j] = anch[((size_t)n*MTOT + idx)*5 + j];
    const float CLIP = 4.135166556742356f;           // log(1000/16)
    float dw = fminf(d[2], CLIP), dh = fminf(d[3], CLIP);
    float x  = d[0]*an[2] + an[0];
    float y  = d[1]*an[3] + an[1];
    float bw = expf(dw)*an[2];
    float bh = expf(dh)*an[3];
    float th = an[4] + d[4]*57.29577951308232f;      // 180/pi
    prop[t*5+0]=x; prop[t*5+1]=y; prop[t*5+2]=bw; prop[t*5+3]=bh; prop[t*5+4]=th;
    score[t] = s;
    validf[t] = (bw >= 4.0f && bh >= 4.0f) ? 1u : 0u;
    area[t] = bw*bh;
    float r = 0.5f*sqrtf(bw*bw + bh*bh);
    xyr[t] = make_float4(x, y, r, 0.0f);
    float ang = th * 0.017453292519943295f;          // pi/180
    float cs = cosf(ang), sn = sinf(ang);
    float hw2 = bw*0.5f, hh2 = bh*0.5f;
    const float sx[4] = {1.f,-1.f,-1.f,1.f};
    const float sy[4] = {1.f,1.f,-1.f,-1.f};
    #pragma unroll
    for (int k = 0; k < 4; ++k) {
      float dxk = sx[k]*hw2, dyk = sy[k]*hh2;
      float cx = (x + cs*dxk) - sn*dyk;
      float cy = (y + sn*dxk) + cs*dyk;
      corn[t*8 + k*2 + 0] = cx;
      corn[t*8 + k*2 + 1] = cy;
    }
  }
}

// ---------------- Sutherland-Hodgman (mirrors reference arithmetic) ----------------
__device__ float quad_inter_area(const float* __restrict__ ca, const float* __restrict__ cb) {
#pragma clang fp contract(off)
  float px[8], py[8];
  int n = 4;
  #pragma unroll
  for (int i = 0; i < 4; ++i) { px[i] = ca[2*i]; py[i] = ca[2*i+1]; }
  for (int e = 0; e < 4; ++e) {
    float p1x = cb[2*e], p1y = cb[2*e+1];
    int e2 = (e+1)&3;
    float dx = cb[2*e2] - p1x, dy = cb[2*e2+1] - p1y;
    float sd[8];
    for (int i = 0; i < n; ++i)
      sd[i] = dx*(py[i]-p1y) - dy*(px[i]-p1x);
    float qx[8], qy[8];
    int m = 0;
    for (int i = 0; i < n; ++i) {
      int nx = (i+1 < n) ? i+1 : 0;
      bool ini = sd[i] >= 0.0f, inn = sd[nx] >= 0.0f;
      if (ini) { qx[m]=px[i]; qy[m]=py[i]; ++m; }
      if (ini != inn) {
        float den = sd[i]-sd[nx];
        float dd = (fabsf(den) < 1e-12f) ? 1e-12f : den;
        float tt = sd[i]/dd;
        qx[m] = px[i] + tt*(px[nx]-px[i]);
        qy[m] = py[i] + tt*(py[nx]-py[i]);
        ++m;
      }
    }
    n = m;
    for (int i = 0; i < n; ++i) { px[i]=qx[i]; py[i]=qy[i]; }
    if (n == 0) break;
  }
  float ssum = 0.0f;
  for (int i = 0; i < n; ++i) {
    int nx = (i+1 < n) ? i+1 : 0;
    ssum += px[i]*py[nx] - px[nx]*py[i];
  }
  return 0.5f*fabsf(ssum);
}

// ---------------- fused circle-test + clip; xyr staged in LDS; 4 rows/block ----------------
__global__ __launch_bounds__(256) void k_iou(const float4* __restrict__ xyr,
                                             const float* __restrict__ corn,
                                             const float* __restrict__ area,
                                             uint64_t* __restrict__ maskT) {
  __shared__ float4 sxyr[KTOP];            // 16000 B, this batch's boxes
  __shared__ uint32_t q[QCAP];             // 16384 B
  __shared__ uint32_t qcnt;
  __shared__ uint32_t mrow32[IOU_WPB*2];   // 4 rows x 16 words x 2 halves
  __shared__ float ca[IOU_ROWS*8];         // own rows' corners
  __shared__ float aa[IOU_ROWS];
  int n = blockIdx.x / IOU_BPB;
  int wbase = (blockIdx.x % IOU_BPB) * IOU_WPB;
  int i0 = wbase >> 4;                     // first owned i-row
  int tid = threadIdx.x, wv = tid >> 6, lane = tid & 63;
  // stage
  for (int t = tid; t < KTOP; t += 256) sxyr[t] = xyr[n*KTOP + t];
  if (tid == 0) qcnt = 0;
  if (tid < IOU_WPB*2) mrow32[tid] = 0;
  if (tid >= 128 && tid < 128 + IOU_ROWS*8)
    ca[tid-128] = corn[(size_t)(n*KTOP + i0)*8 + (tid-128)];
  if (tid >= 160 && tid < 160 + IOU_ROWS)
    aa[tid-160] = area[n*KTOP + i0 + (tid-160)];
  __syncthreads();
  // scan: 16 words per wave, all LDS reads
  for (int w = wv; w < IOU_WPB; w += 4) {
    int word = wbase + w;
    int i = word >> 4;               // word / NWORDS
    int jb = word & 15;              // word % NWORDS
    if (jb*64 + 63 <= i) continue;   // no j > i in this word
    int j = jb*64 + lane;
    bool hit = false;
    if (j > i && j < KTOP) {
      float4 a = sxyr[i];            // wave-uniform LDS broadcast
      float4 b = sxyr[j];
      float dx = a.x - b.x, dy = a.y - b.y;
      float rs = a.z + b.z;
      hit = (dx*dx + dy*dy) <= rs*rs*1.0001f;
    }
    unsigned long long bal = __ballot(hit);
    if (!bal) continue;
    int tot = __popcll(bal);
    int leader = __ffsll(bal) - 1;
    uint32_t base = 0;
    if (lane == leader) base = atomicAdd(&qcnt, (uint32_t)tot);
    base = __shfl(base, leader);
    if (hit) {
      int pos = __popcll(bal & ((1ull << lane) - 1ull));
      q[base + pos] = ((uint32_t)i << 10) | (uint32_t)j;
    }
  }
  __syncthreads();
  uint32_t cnt = qcnt;
  for (uint32_t t = tid; t < cnt; t += 256) {
    uint32_t code = q[t];
    int i = code >> 10, j = code & 1023;
    int bj = n*KTOP + j;
    float inter = quad_inter_area(&ca[(i - i0)*8], &corn[(size_t)bj*8]);
    float uni = (aa[i - i0] + area[bj]) - inter;
    if (inter / fmaxf(uni, 1e-8f) > NMS_TH)
      atomicOr(&mrow32[((i - i0)*NWORDS + (j >> 6))*2 + ((j >> 5) & 1)],
               1u << (j & 31));
  }
  __syncthreads();
  // store transposed: maskT[n][l][row] (disjoint cells, full overwrite)
  uint64_t* dstT = &maskT[(size_t)n*NWORDS*KTOP];
  for (int t = tid; t < IOU_WPB; t += 256) {
    int r = t >> 4, l = t & 15;
    dstT[(size_t)l*KTOP + i0 + r] =
      (uint64_t)mrow32[(r*NWORDS + l)*2] | ((uint64_t)mrow32[(r*NWORDS + l)*2 + 1] << 32);
  }
}

// ---------------- blocked greedy NMS: no staging, readlane diag, prefetch ----------------
__global__ __launch_bounds__(256) void k_nms(const uint32_t* __restrict__ validf,
                                             const uint64_t* __restrict__ maskT,
                                             const float* __restrict__ prop,
                                             const float* __restrict__ score,
                                             float* __restrict__ out) {
  __shared__ uint64_t kw[NWORDS];
  int n = blockIdx.x;
  int tid = threadIdx.x, wv = tid >> 6, lane = tid & 63;
  const uint64_t* MT = &maskT[(size_t)n*NWORDS*KTOP];

  // wave0: preload all 16 diag words (lane holds row b*64+lane's word b)
  uint64_t dreg[NWORDS];
  if (wv == 0) {
    #pragma unroll
    for (int b = 0; b < NWORDS; ++b) {
      int row = b*64 + lane;
      dreg[b] = MT[(size_t)b*KTOP + (row < KTOP ? row : 0)];
    }
    #pragma unroll
    for (int w = 0; w < NWORDS; ++w) {
      int k = w*64 + lane;
      uint32_t v = (k < KTOP) ? validf[n*KTOP + k] : 0u;
      unsigned long long bm = __ballot(v != 0u);
      if (lane == 0) kw[w] = (uint64_t)bm;
    }
  }
  __syncthreads();

  // cross-apply double buffer: phase b uses rows b*64+lane at words l=b+1+wv+4k
  uint64_t cur0=0, cur1=0, cur2=0, cur3=0;
  {
    int row = lane;            // phase 0 rows
    int l0 = 1 + wv;
    cur0 = (l0    < NWORDS) ? MT[(size_t)(l0   )*KTOP + row] : 0ull;
    cur1 = (l0+4  < NWORDS) ? MT[(size_t)(l0+4 )*KTOP + row] : 0ull;
    cur2 = (l0+8  < NWORDS) ? MT[(size_t)(l0+8 )*KTOP + row] : 0ull;
    cur3 = (l0+12 < NWORDS) ? MT[(size_t)(l0+12)*KTOP + row] : 0ull;
  }

  for (int b = 0; b < NWORDS; ++b) {
    // --- diag resolve (wave 0): readlane + branchless SALU chain, uniform ---
    if (wv == 0) {
      uint64_t alive = kw[b];
      uint32_t dlo = (uint32_t)dreg[b], dhi = (uint32_t)(dreg[b] >> 32);
      #pragma unroll
      for (int i = 0; i < 64; ++i) {
        uint32_t lo = __builtin_amdgcn_readlane(dlo, i);
        uint32_t hi = __builtin_amdgcn_readlane(dhi, i);
        uint64_t d = ((uint64_t)hi << 32) | lo;
        uint64_t m = (uint64_t)0 - ((alive >> i) & 1ull);
        alive &= ~(d & m);
      }
      if (lane == 0) kw[b] = alive;
    }
    // --- prefetch next phase's apply rows (alive-independent) ---
    uint64_t nxt0=0, nxt1=0, nxt2=0, nxt3=0;
    if (b + 2 < NWORDS) {
      int row = (b+1)*64 + lane;     // <= 959, in range
      int l0 = b + 2 + wv;
      nxt0 = (l0    < NWORDS) ? MT[(size_t)(l0   )*KTOP + row] : 0ull;
      nxt1 = (l0+4  < NWORDS) ? MT[(size_t)(l0+4 )*KTOP + row] : 0ull;
      nxt2 = (l0+8  < NWORDS) ? MT[(size_t)(l0+8 )*KTOP + row] : 0ull;
      nxt3 = (l0+12 < NWORDS) ? MT[(size_t)(l0+12)*KTOP + row] : 0ull;
    }
    __syncthreads();
    if (b < NWORDS-1) {
      uint64_t alive = kw[b];
      uint64_t me = (uint64_t)0 - ((alive >> lane) & 1ull);
      uint64_t mv0 = cur0 & me, mv1 = cur1 & me, mv2 = cur2 & me, mv3 = cur3 & me;
      #pragma unroll
      for (int s = 1; s < 64; s <<= 1) {
        mv0 |= __shfl_xor(mv0, s);
        mv1 |= __shfl_xor(mv1, s);
        mv2 |= __shfl_xor(mv2, s);
        mv3 |= __shfl_xor(mv3, s);
      }
      if (lane == 0) {
        int l0 = b + 1 + wv;
        if (l0    < NWORDS) kw[l0   ] &= ~mv0;
        if (l0+4  < NWORDS) kw[l0+4 ] &= ~mv1;
        if (l0+8  < NWORDS) kw[l0+8 ] &= ~mv2;
        if (l0+12 < NWORDS) kw[l0+12] &= ~mv3;
      }
      __syncthreads();
    }
    cur0=nxt0; cur1=nxt1; cur2=nxt2; cur3=nxt3;
  }

  // rank <= POSTN trim (thread 0), then all threads write output
  if (tid == 0) {
    int prev = 0;
    #pragma unroll
    for (int t = 0; t < NWORDS; ++t) {
      uint64_t wrd = kw[t];
      int pc = __popcll(wrd);
      if (prev >= POSTN) wrd = 0;
      else if (prev + pc > POSTN) {
        int allow = POSTN - prev;
        while (__popcll(wrd) > allow) wrd &= ~(1ull << (63 - __clzll(wrd)));
      }
      prev += __popcll(wrd);
      kw[t] = wrd;
    }
  }
  __syncthreads();
  for (int k = tid; k < KTOP; k += 256) {
    bool bb = (kw[k>>6] >> (k&63)) & 1ull;
    float f = bb ? 1.0f : 0.0f;
    int t = n*KTOP + k;
    #pragma unroll
    for (int c = 0; c < 5; ++c) out[t*6 + c] = prop[t*5 + c] * f;
    out[t*6 + 5] = score[t] * f;
  }
}

extern "C" void kernel_launch(void* const* d_in, const int* in_sizes, int n_in,
                              void* d_out, int out_size, void* d_ws, size_t ws_size,
                              hipStream_t stream) {
  const float* obj  = (const float*)d_in[0];
  const float* breg = (const float*)d_in[1];
  const float* anch = (const float*)d_in[2];
  float* out = (float*)d_out;
  char* ws = (char*)d_ws;

  uint32_t* hist  = (uint32_t*)(ws + OFF_HIST);
  uint32_t* cnt   = (uint32_t*)(ws + OFF_CNT);
  uint32_t* thr   = (uint32_t*)(ws + OFF_THR);
  uint64_t* cand  = (uint64_t*)(ws + OFF_CAND);
  float*    prop  = (float*)(ws + OFF_PROP);
  float*    score = (float*)(ws + OFF_SCORE);
  float*    corn  = (float*)(ws + OFF_CORN);
  float*    area  = (float*)(ws + OFF_AREA);
  uint32_t* validf= (uint32_t*)(ws + OFF_VALID);
  float4*   xyr   = (float4*)(ws + OFF_XYR);
  uint64_t* maskT = (uint64_t*)(ws + OFF_MASK);

  hipMemsetAsync(ws, 0, OFF_CAND, stream);   // hist + cnt + thr

  int nt = NBATCH*MTOT;
  k_hist   <<<NBATCH*BPB, 256, 0, stream>>>(obj, hist);
  k_thresh <<<NBATCH, 256, 0, stream>>>(hist, thr);
  k_compact<<<(nt+255)/256, 256, 0, stream>>>(obj, thr, cand, cnt);
  k_sortdec<<<NBATCH, 1024, 0, stream>>>(cand, cnt, breg, anch, prop, score, corn, area, xyr, validf);
  k_iou    <<<NBATCH*IOU_BPB, 256, 0, stream>>>(xyr, corn, area, maskT);
  k_nms    <<<NBATCH, 256, 0, stream>>>(validf, maskT, prop, score, out);
}

// Round 10
// 170.084 us; speedup vs baseline: 1.6046x; 1.1541x over previous
//
#include <hip/hip_runtime.h>
#include <stdint.h>

// RPN rotated-NMS post-processor, MI355X. Round 10: register-resident
// Sutherland-Hodgman clipper (constant-index arrays + select-chain emit;
// kills the scratch traffic that dominated k_iou). Rest unchanged from r9.

#define NBATCH 4
#define AANCH 15
#define HDIM 200
#define WDIM 200
#define MTOT (AANCH*HDIM*WDIM)   // 600000
#define KTOP 1000
#define POSTN 300
#define NBINS 16384
#define CAND_CAP 2048
#define NWORDS 16                // ceil(1000/64)
#define NMS_TH 0.7f
#define BPB 75                   // blocks per batch for hist
#define CHUNK (MTOT/BPB)         // 8000
#define IOU_ROWS 4               // i-rows per iou block
#define IOU_BPB 250              // iou blocks per batch
#define IOU_WPB (IOU_ROWS*NWORDS) // 64 mask words per iou block
#define QCAP 4096                // provable max survivors (4 rows x <=1000 j)

// ---------------- ws layout ----------------
constexpr size_t OFF_HIST = 0;
constexpr size_t SZ_HIST  = (size_t)NBATCH*NBINS*4;                 // 262144
constexpr size_t OFF_CNT  = OFF_HIST + SZ_HIST;
constexpr size_t OFF_THR  = OFF_CNT + 256;
constexpr size_t OFF_CAND = OFF_THR + 256;
constexpr size_t OFF_PROP = OFF_CAND + (size_t)NBATCH*CAND_CAP*8;
constexpr size_t OFF_SCORE= OFF_PROP + (size_t)NBATCH*KTOP*5*4;
constexpr size_t OFF_CORN = OFF_SCORE+ (size_t)NBATCH*KTOP*4;
constexpr size_t OFF_AREA = OFF_CORN + (size_t)NBATCH*KTOP*8*4;
constexpr size_t OFF_VALID= OFF_AREA + (size_t)NBATCH*KTOP*4;
constexpr size_t OFF_XYR  = OFF_VALID+ (size_t)NBATCH*KTOP*4;
constexpr size_t OFF_MASK = OFF_XYR  + (size_t)NBATCH*KTOP*16;      // maskT [n][l][row]

__device__ __forceinline__ float sigmoid_ref(float x) {
  return 1.0f / (1.0f + expf(-x));
}

// ---------------- histogram: LDS-privatized ----------------
__global__ __launch_bounds__(256) void k_hist(const float* __restrict__ obj,
                                              uint32_t* __restrict__ hist) {
  __shared__ uint32_t h[NBINS];
  for (int i = threadIdx.x; i < NBINS; i += 256) h[i] = 0;
  __syncthreads();
  int n = blockIdx.x / BPB, c = blockIdx.x % BPB;
  const float4* p = (const float4*)(obj + (size_t)n*MTOT + (size_t)c*CHUNK);
  const int nq = CHUNK/4;
  for (int q = threadIdx.x; q < nq; q += 256) {
    float4 v = p[q];
    #pragma unroll
    for (int k = 0; k < 4; ++k) {
      float x = (&v.x)[k];
      uint32_t bits = __float_as_uint(sigmoid_ref(x));
      uint32_t bin = bits >> 16; if (bin > NBINS-1) bin = NBINS-1;
      atomicAdd(&h[bin], 1u);
    }
  }
  __syncthreads();
  for (int i = threadIdx.x; i < NBINS; i += 256) {
    uint32_t v = h[i];
    if (v) atomicAdd(&hist[n*NBINS + i], v);
  }
}

// ---------------- threshold ----------------
__global__ __launch_bounds__(256) void k_thresh(const uint32_t* __restrict__ hist,
                                                uint32_t* __restrict__ thr) {
  __shared__ uint32_t ps[256];
  int n = blockIdx.x, tid = threadIdx.x;
  uint32_t s = 0;
  const uint32_t* hb = &hist[n*NBINS];
  #pragma unroll 4
  for (int b = tid*64; b < tid*64+64; ++b) s += hb[b];
  ps[tid] = s;
  __syncthreads();
  if (tid == 0) {
    uint32_t cum = 0; int cidx = -1;
    for (int cc = 255; cc >= 0; --cc) {
      if (cum + ps[cc] >= KTOP) { cidx = cc; break; }
      cum += ps[cc];
    }
    if (cidx < 0) { thr[n] = 0u; return; }
    int b = cidx*64+63;
    for (; b >= cidx*64; --b) { cum += hb[b]; if (cum >= KTOP) break; }
    thr[n] = (uint32_t)(b < 0 ? 0 : b);
  }
}

// ---------------- compact candidates (wave-aggregated atomics) ----------------
__global__ __launch_bounds__(256) void k_compact(const float* __restrict__ obj,
                                                 const uint32_t* __restrict__ thr,
                                                 uint64_t* __restrict__ cand,
                                                 uint32_t* __restrict__ cnt) {
  int t = blockIdx.x*blockDim.x + threadIdx.x;
  if (t >= NBATCH*MTOT) return;
  int n = t / MTOT;           // wave-uniform: MTOT % 64 == 0
  int rem = t % MTOT;
  int lane = threadIdx.x & 63;
  float x = obj[t];
  uint32_t bits = __float_as_uint(sigmoid_ref(x));
  uint32_t bin = bits >> 16; if (bin > NBINS-1) bin = NBINS-1;
  bool hit = (bin >= thr[n]);
  unsigned long long bal = __ballot(hit);
  if (!bal) return;
  int tot = __popcll(bal);
  int leader = __ffsll(bal) - 1;
  uint32_t base = 0;
  if (lane == leader) base = atomicAdd(&cnt[n], (uint32_t)tot);
  base = __shfl(base, leader);
  if (hit) {
    uint32_t p = base + (uint32_t)__popcll(bal & ((1ull << lane) - 1ull));
    if (p < CAND_CAP) {
      int hw = rem % (HDIM*WDIM);
      int a  = rem / (HDIM*WDIM);
      uint32_t fidx = (uint32_t)(hw*AANCH + a);
      cand[(size_t)n*CAND_CAP + p] = ((uint64_t)bits << 32) | (uint32_t)(~fidx);
    }
  }
}

// ---------------- bitonic sort (2048) + fused decode epilogue ----------------
__global__ __launch_bounds__(1024) void k_sortdec(const uint64_t* __restrict__ cand,
                                                  const uint32_t* __restrict__ cnt,
                                                  const float* __restrict__ breg,
                                                  const float* __restrict__ anch,
                                                  float* __restrict__ prop,
                                                  float* __restrict__ score,
                                                  float* __restrict__ corn,
                                                  float* __restrict__ area,
                                                  float4* __restrict__ xyr,
                                                  uint32_t* __restrict__ validf) {
  __shared__ uint64_t sk[CAND_CAP];
  int n = blockIdx.x, tid = threadIdx.x;
  uint32_t c = cnt[n]; if (c > CAND_CAP) c = CAND_CAP;
  #pragma unroll
  for (int i = tid; i < CAND_CAP; i += 1024)
    sk[i] = (i < (int)c) ? cand[(size_t)n*CAND_CAP + i] : 0ull;
  __syncthreads();
  for (int len = 2; len <= CAND_CAP; len <<= 1) {
    for (int str = len >> 1; str > 0; str >>= 1) {
      #pragma unroll
      for (int i = tid; i < CAND_CAP; i += 1024) {
        int j = i ^ str;
        if (j > i) {
          bool up = ((i & len) == 0);
          uint64_t x = sk[i], y = sk[j];
          if ((x > y) == up) { sk[i] = y; sk[j] = x; }
        }
      }
      __syncthreads();
    }
  }
  // ---- decode entry `tid` (rank tid, descending) ----
  if (tid < KTOP) {
#pragma clang fp contract(off)
    int t = n*KTOP + tid;
    uint64_t key = sk[CAND_CAP-1-tid];
    uint32_t idx = ~(uint32_t)(key & 0xFFFFFFFFull);
    float s = __uint_as_float((uint32_t)(key >> 32));
    int a = idx % AANCH, pos = idx / AANCH;
    int w = pos % WDIM, h = pos / WDIM;
    float d[5], an[5];
    #pragma unroll
    for (int j = 0; j < 5; ++j)
      d[j] = breg[((n*(AANCH*5) + (a*5+j))*HDIM + h)*WDIM + w];
    #pragma unroll
    for (int j = 0; j < 5; ++j)
      an[j] = anch[((size_t)n*MTOT + idx)*5 + j];
    const float CLIP = 4.135166556742356f;           // log(1000/16)
    float dw = fminf(d[2], CLIP), dh = fminf(d[3], CLIP);
    float x  = d[0]*an[2] + an[0];
    float y  = d[1]*an[3] + an[1];
    float bw = expf(dw)*an[2];
    float bh = expf(dh)*an[3];
    float th = an[4] + d[4]*57.29577951308232f;      // 180/pi
    prop[t*5+0]=x; prop[t*5+1]=y; prop[t*5+2]=bw; prop[t*5+3]=bh; prop[t*5+4]=th;
    score[t] = s;
    validf[t] = (bw >= 4.0f && bh >= 4.0f) ? 1u : 0u;
    area[t] = bw*bh;
    float r = 0.5f*sqrtf(bw*bw + bh*bh);
    xyr[t] = make_float4(x, y, r, 0.0f);
    float ang = th * 0.017453292519943295f;          // pi/180
    float cs = cosf(ang), sn = sinf(ang);
    float hw2 = bw*0.5f, hh2 = bh*0.5f;
    const float sx[4] = {1.f,-1.f,-1.f,1.f};
    const float sy[4] = {1.f,1.f,-1.f,-1.f};
    #pragma unroll
    for (int k = 0; k < 4; ++k) {
      float dxk = sx[k]*hw2, dyk = sy[k]*hh2;
      float cx = (x + cs*dxk) - sn*dyk;
      float cy = (y + sn*dxk) + cs*dyk;
      corn[t*8 + k*2 + 0] = cx;
      corn[t*8 + k*2 + 1] = cy;
    }
  }
}

// ---------------- Sutherland-Hodgman, register-resident ----------------
// Identical arithmetic & emit order to the reference; all array indices are
// compile-time constants (full unroll + guards + select-chain append) so the
// polygon lives in VGPRs, not scratch.
__device__ __forceinline__ float quad_inter_area(const float* __restrict__ ca,
                                                 const float* __restrict__ cb) {
#pragma clang fp contract(off)
  float px[8], py[8];
  int n = 4;
  #pragma unroll
  for (int i = 0; i < 4; ++i) { px[i] = ca[2*i]; py[i] = ca[2*i+1]; }
  #pragma unroll
  for (int i = 4; i < 8; ++i) { px[i] = 0.0f; py[i] = 0.0f; }
  #pragma unroll
  for (int e = 0; e < 4; ++e) {
    float p1x = cb[2*e], p1y = cb[2*e+1];
    int e2 = (e+1)&3;
    float dx = cb[2*e2] - p1x, dy = cb[2*e2+1] - p1y;
    float sd[8];
    #pragma unroll
    for (int i = 0; i < 8; ++i)
      sd[i] = dx*(py[i]-p1y) - dy*(px[i]-p1x);   // only i<n consumed
    float qx[8], qy[8];
    #pragma unroll
    for (int i = 0; i < 8; ++i) { qx[i] = 0.0f; qy[i] = 0.0f; }
    int m = 0;
    #pragma unroll
    for (int i = 0; i < 8; ++i) {
      if (i < n) {
        bool wrap = !(i+1 < n);
        float sdi = sd[i];
        float sdn = wrap ? sd[0] : sd[(i+1)&7];
        float pnx = wrap ? px[0] : px[(i+1)&7];
        float pny = wrap ? py[0] : py[(i+1)&7];
        bool ini = sdi >= 0.0f, inn = sdn >= 0.0f;
        if (ini) {
          float vx = px[i], vy = py[i];
          #pragma unroll
          for (int k = 0; k < 8; ++k) if (m == k) { qx[k] = vx; qy[k] = vy; }
          ++m;
        }
        if (ini != inn) {
          float den = sdi - sdn;
          float dd = (fabsf(den) < 1e-12f) ? 1e-12f : den;
          float tt = sdi/dd;
          float vx = px[i] + tt*(pnx - px[i]);
          float vy = py[i] + tt*(pny - py[i]);
          #pragma unroll
          for (int k = 0; k < 8; ++k) if (m == k) { qx[k] = vx; qy[k] = vy; }
          ++m;
        }
      }
    }
    n = m;
    #pragma unroll
    for (int i = 0; i < 8; ++i) { px[i] = qx[i]; py[i] = qy[i]; }
  }
  float ssum = 0.0f;
  #pragma unroll
  for (int i = 0; i < 8; ++i) {
    if (i < n) {
      bool wrap = !(i+1 < n);
      float pnx = wrap ? px[0] : px[(i+1)&7];
      float pny = wrap ? py[0] : py[(i+1)&7];
      ssum += px[i]*pny - pnx*py[i];
    }
  }
  return 0.5f*fabsf(ssum);
}

// ---------------- fused circle-test + clip; xyr staged in LDS; 4 rows/block ----------------
__global__ __launch_bounds__(256) void k_iou(const float4* __restrict__ xyr,
                                             const float* __restrict__ corn,
                                             const float* __restrict__ area,
                                             uint64_t* __restrict__ maskT) {
  __shared__ float4 sxyr[KTOP];            // 16000 B, this batch's boxes
  __shared__ uint32_t q[QCAP];             // 16384 B
  __shared__ uint32_t qcnt;
  __shared__ uint32_t mrow32[IOU_WPB*2];   // 4 rows x 16 words x 2 halves
  __shared__ float ca[IOU_ROWS*8];         // own rows' corners
  __shared__ float aa[IOU_ROWS];
  int n = blockIdx.x / IOU_BPB;
  int wbase = (blockIdx.x % IOU_BPB) * IOU_WPB;
  int i0 = wbase >> 4;                     // first owned i-row
  int tid = threadIdx.x, wv = tid >> 6, lane = tid & 63;
  // stage
  for (int t = tid; t < KTOP; t += 256) sxyr[t] = xyr[n*KTOP + t];
  if (tid == 0) qcnt = 0;
  if (tid < IOU_WPB*2) mrow32[tid] = 0;
  if (tid >= 128 && tid < 128 + IOU_ROWS*8)
    ca[tid-128] = corn[(size_t)(n*KTOP + i0)*8 + (tid-128)];
  if (tid >= 160 && tid < 160 + IOU_ROWS)
    aa[tid-160] = area[n*KTOP + i0 + (tid-160)];
  __syncthreads();
  // scan: 16 words per wave, all LDS reads
  for (int w = wv; w < IOU_WPB; w += 4) {
    int word = wbase + w;
    int i = word >> 4;               // word / NWORDS
    int jb = word & 15;              // word % NWORDS
    if (jb*64 + 63 <= i) continue;   // no j > i in this word
    int j = jb*64 + lane;
    bool hit = false;
    if (j > i && j < KTOP) {
      float4 a = sxyr[i];            // wave-uniform LDS broadcast
      float4 b = sxyr[j];
      float dx = a.x - b.x, dy = a.y - b.y;
      float rs = a.z + b.z;
      hit = (dx*dx + dy*dy) <= rs*rs*1.0001f;
    }
    unsigned long long bal = __ballot(hit);
    if (!bal) continue;
    int tot = __popcll(bal);
    int leader = __ffsll(bal) - 1;
    uint32_t base = 0;
    if (lane == leader) base = atomicAdd(&qcnt, (uint32_t)tot);
    base = __shfl(base, leader);
    if (hit) {
      int pos = __popcll(bal & ((1ull << lane) - 1ull));
      q[base + pos] = ((uint32_t)i << 10) | (uint32_t)j;
    }
  }
  __syncthreads();
  uint32_t cnt = qcnt;
  for (uint32_t t = tid; t < cnt; t += 256) {
    uint32_t code = q[t];
    int i = code >> 10, j = code & 1023;
    int bj = n*KTOP + j;
    float inter = quad_inter_area(&ca[(i - i0)*8], &corn[(size_t)bj*8]);
    float uni = (aa[i - i0] + area[bj]) - inter;
    if (inter / fmaxf(uni, 1e-8f) > NMS_TH)
      atomicOr(&mrow32[((i - i0)*NWORDS + (j >> 6))*2 + ((j >> 5) & 1)],
               1u << (j & 31));
  }
  __syncthreads();
  // store transposed: maskT[n][l][row] (disjoint cells, full overwrite)
  uint64_t* dstT = &maskT[(size_t)n*NWORDS*KTOP];
  for (int t = tid; t < IOU_WPB; t += 256) {
    int r = t >> 4, l = t & 15;
    dstT[(size_t)l*KTOP + i0 + r] =
      (uint64_t)mrow32[(r*NWORDS + l)*2] | ((uint64_t)mrow32[(r*NWORDS + l)*2 + 1] << 32);
  }
}

// ---------------- blocked greedy NMS: no staging, readlane diag, prefetch ----------------
__global__ __launch_bounds__(256) void k_nms(const uint32_t* __restrict__ validf,
                                             const uint64_t* __restrict__ maskT,
                                             const float* __restrict__ prop,
                                             const float* __restrict__ score,
                                             float* __restrict__ out) {
  __shared__ uint64_t kw[NWORDS];
  int n = blockIdx.x;
  int tid = threadIdx.x, wv = tid >> 6, lane = tid & 63;
  const uint64_t* MT = &maskT[(size_t)n*NWORDS*KTOP];

  // wave0: preload all 16 diag words (lane holds row b*64+lane's word b)
  uint64_t dreg[NWORDS];
  if (wv == 0) {
    #pragma unroll
    for (int b = 0; b < NWORDS; ++b) {
      int row = b*64 + lane;
      dreg[b] = MT[(size_t)b*KTOP + (row < KTOP ? row : 0)];
    }
    #pragma unroll
    for (int w = 0; w < NWORDS; ++w) {
      int k = w*64 + lane;
      uint32_t v = (k < KTOP) ? validf[n*KTOP + k] : 0u;
      unsigned long long bm = __ballot(v != 0u);
      if (lane == 0) kw[w] = (uint64_t)bm;
    }
  }
  __syncthreads();

  // cross-apply double buffer: phase b uses rows b*64+lane at words l=b+1+wv+4k
  uint64_t cur0=0, cur1=0, cur2=0, cur3=0;
  {
    int row = lane;            // phase 0 rows
    int l0 = 1 + wv;
    cur0 = (l0    < NWORDS) ? MT[(size_t)(l0   )*KTOP + row] : 0ull;
    cur1 = (l0+4  < NWORDS) ? MT[(size_t)(l0+4 )*KTOP + row] : 0ull;
    cur2 = (l0+8  < NWORDS) ? MT[(size_t)(l0+8 )*KTOP + row] : 0ull;
    cur3 = (l0+12 < NWORDS) ? MT[(size_t)(l0+12)*KTOP + row] : 0ull;
  }

  for (int b = 0; b < NWORDS; ++b) {
    // --- diag resolve (wave 0): readlane + branchless SALU chain, uniform ---
    if (wv == 0) {
      uint64_t alive = kw[b];
      uint32_t dlo = (uint32_t)dreg[b], dhi = (uint32_t)(dreg[b] >> 32);
      #pragma unroll
      for (int i = 0; i < 64; ++i) {
        uint32_t lo = __builtin_amdgcn_readlane(dlo, i);
        uint32_t hi = __builtin_amdgcn_readlane(dhi, i);
        uint64_t d = ((uint64_t)hi << 32) | lo;
        uint64_t m = (uint64_t)0 - ((alive >> i) & 1ull);
        alive &= ~(d & m);
      }
      if (lane == 0) kw[b] = alive;
    }
    // --- prefetch next phase's apply rows (alive-independent) ---
    uint64_t nxt0=0, nxt1=0, nxt2=0, nxt3=0;
    if (b + 2 < NWORDS) {
      int row = (b+1)*64 + lane;     // <= 959, in range
      int l0 = b + 2 + wv;
      nxt0 = (l0    < NWORDS) ? MT[(size_t)(l0   )*KTOP + row] : 0ull;
      nxt1 = (l0+4  < NWORDS) ? MT[(size_t)(l0+4 )*KTOP + row] : 0ull;
      nxt2 = (l0+8  < NWORDS) ? MT[(size_t)(l0+8 )*KTOP + row] : 0ull;
      nxt3 = (l0+12 < NWORDS) ? MT[(size_t)(l0+12)*KTOP + row] : 0ull;
    }
    __syncthreads();
    if (b < NWORDS-1) {
      uint64_t alive = kw[b];
      uint64_t me = (uint64_t)0 - ((alive >> lane) & 1ull);
      uint64_t mv0 = cur0 & me, mv1 = cur1 & me, mv2 = cur2 & me, mv3 = cur3 & me;
      #pragma unroll
      for (int s = 1; s < 64; s <<= 1) {
        mv0 |= __shfl_xor(mv0, s);
        mv1 |= __shfl_xor(mv1, s);
        mv2 |= __shfl_xor(mv2, s);
        mv3 |= __shfl_xor(mv3, s);
      }
      if (lane == 0) {
        int l0 = b + 1 + wv;
        if (l0    < NWORDS) kw[l0   ] &= ~mv0;
        if (l0+4  < NWORDS) kw[l0+4 ] &= ~mv1;
        if (l0+8  < NWORDS) kw[l0+8 ] &= ~mv2;
        if (l0+12 < NWORDS) kw[l0+12] &= ~mv3;
      }
      __syncthreads();
    }
    cur0=nxt0; cur1=nxt1; cur2=nxt2; cur3=nxt3;
  }

  // rank <= POSTN trim (thread 0), then all threads write output
  if (tid == 0) {
    int prev = 0;
    #pragma unroll
    for (int t = 0; t < NWORDS; ++t) {
      uint64_t wrd = kw[t];
      int pc = __popcll(wrd);
      if (prev >= POSTN) wrd = 0;
      else if (prev + pc > POSTN) {
        int allow = POSTN - prev;
        while (__popcll(wrd) > allow) wrd &= ~(1ull << (63 - __clzll(wrd)));
      }
      prev += __popcll(wrd);
      kw[t] = wrd;
    }
  }
  __syncthreads();
  for (int k = tid; k < KTOP; k += 256) {
    bool bb = (kw[k>>6] >> (k&63)) & 1ull;
    float f = bb ? 1.0f : 0.0f;
    int t = n*KTOP + k;
    #pragma unroll
    for (int c = 0; c < 5; ++c) out[t*6 + c] = prop[t*5 + c] * f;
    out[t*6 + 5] = score[t] * f;
  }
}

extern "C" void kernel_launch(void* const* d_in, const int* in_sizes, int n_in,
                              void* d_out, int out_size, void* d_ws, size_t ws_size,
                              hipStream_t stream) {
  const float* obj  = (const float*)d_in[0];
  const float* breg = (const float*)d_in[1];
  const float* anch = (const float*)d_in[2];
  float* out = (float*)d_out;
  char* ws = (char*)d_ws;

  uint32_t* hist  = (uint32_t*)(ws + OFF_HIST);
  uint32_t* cnt   = (uint32_t*)(ws + OFF_CNT);
  uint32_t* thr   = (uint32_t*)(ws + OFF_THR);
  uint64_t* cand  = (uint64_t*)(ws + OFF_CAND);
  float*    prop  = (float*)(ws + OFF_PROP);
  float*    score = (float*)(ws + OFF_SCORE);
  float*    corn  = (float*)(ws + OFF_CORN);
  float*    area  = (float*)(ws + OFF_AREA);
  uint32_t* validf= (uint32_t*)(ws + OFF_VALID);
  float4*   xyr   = (float4*)(ws + OFF_XYR);
  uint64_t* maskT = (uint64_t*)(ws + OFF_MASK);

  hipMemsetAsync(ws, 0, OFF_CAND, stream);   // hist + cnt + thr

  int nt = NBATCH*MTOT;
  k_hist   <<<NBATCH*BPB, 256, 0, stream>>>(obj, hist);
  k_thresh <<<NBATCH, 256, 0, stream>>>(hist, thr);
  k_compact<<<(nt+255)/256, 256, 0, stream>>>(obj, thr, cand, cnt);
  k_sortdec<<<NBATCH, 1024, 0, stream>>>(cand, cnt, breg, anch, prop, score, corn, area, xyr, validf);
  k_iou    <<<NBATCH*IOU_BPB, 256, 0, stream>>>(xyr, corn, area, maskT);
  k_nms    <<<NBATCH, 256, 0, stream>>>(validf, maskT, prop, score, out);
}

// Round 11
// 147.437 us; speedup vs baseline: 1.8511x; 1.1536x over previous
//
#include <hip/hip_runtime.h>
#include <stdint.h>

// RPN rotated-NMS post-processor, MI355X. Round 11: k_compact vectorized
// (float4 loads) + block-aggregated atomics (1 global atomic per block).
// Rest unchanged from r10.

#define NBATCH 4
#define AANCH 15
#define HDIM 200
#define WDIM 200
#define MTOT (AANCH*HDIM*WDIM)   // 600000
#define KTOP 1000
#define POSTN 300
#define NBINS 16384
#define CAND_CAP 2048
#define NWORDS 16                // ceil(1000/64)
#define NMS_TH 0.7f
#define BPB 75                   // blocks per batch for hist
#define CHUNK (MTOT/BPB)         // 8000
#define IOU_ROWS 4               // i-rows per iou block
#define IOU_BPB 250              // iou blocks per batch
#define IOU_WPB (IOU_ROWS*NWORDS) // 64 mask words per iou block
#define QCAP 4096                // provable max survivors (4 rows x <=1000 j)
#define NQ4 (MTOT/4)             // 150000 float4 per batch
#define CBLK ((NQ4+255)/256)     // 586 compact blocks per batch

// ---------------- ws layout ----------------
constexpr size_t OFF_HIST = 0;
constexpr size_t SZ_HIST  = (size_t)NBATCH*NBINS*4;                 // 262144
constexpr size_t OFF_CNT  = OFF_HIST + SZ_HIST;
constexpr size_t OFF_THR  = OFF_CNT + 256;
constexpr size_t OFF_CAND = OFF_THR + 256;
constexpr size_t OFF_PROP = OFF_CAND + (size_t)NBATCH*CAND_CAP*8;
constexpr size_t OFF_SCORE= OFF_PROP + (size_t)NBATCH*KTOP*5*4;
constexpr size_t OFF_CORN = OFF_SCORE+ (size_t)NBATCH*KTOP*4;
constexpr size_t OFF_AREA = OFF_CORN + (size_t)NBATCH*KTOP*8*4;
constexpr size_t OFF_VALID= OFF_AREA + (size_t)NBATCH*KTOP*4;
constexpr size_t OFF_XYR  = OFF_VALID+ (size_t)NBATCH*KTOP*4;
constexpr size_t OFF_MASK = OFF_XYR  + (size_t)NBATCH*KTOP*16;      // maskT [n][l][row]

__device__ __forceinline__ float sigmoid_ref(float x) {
  return 1.0f / (1.0f + expf(-x));
}

// ---------------- histogram: LDS-privatized ----------------
__global__ __launch_bounds__(256) void k_hist(const float* __restrict__ obj,
                                              uint32_t* __restrict__ hist) {
  __shared__ uint32_t h[NBINS];
  for (int i = threadIdx.x; i < NBINS; i += 256) h[i] = 0;
  __syncthreads();
  int n = blockIdx.x / BPB, c = blockIdx.x % BPB;
  const float4* p = (const float4*)(obj + (size_t)n*MTOT + (size_t)c*CHUNK);
  const int nq = CHUNK/4;
  for (int q = threadIdx.x; q < nq; q += 256) {
    float4 v = p[q];
    #pragma unroll
    for (int k = 0; k < 4; ++k) {
      float x = (&v.x)[k];
      uint32_t bits = __float_as_uint(sigmoid_ref(x));
      uint32_t bin = bits >> 16; if (bin > NBINS-1) bin = NBINS-1;
      atomicAdd(&h[bin], 1u);
    }
  }
  __syncthreads();
  for (int i = threadIdx.x; i < NBINS; i += 256) {
    uint32_t v = h[i];
    if (v) atomicAdd(&hist[n*NBINS + i], v);
  }
}

// ---------------- threshold ----------------
__global__ __launch_bounds__(256) void k_thresh(const uint32_t* __restrict__ hist,
                                                uint32_t* __restrict__ thr) {
  __shared__ uint32_t ps[256];
  int n = blockIdx.x, tid = threadIdx.x;
  uint32_t s = 0;
  const uint32_t* hb = &hist[n*NBINS];
  #pragma unroll 4
  for (int b = tid*64; b < tid*64+64; ++b) s += hb[b];
  ps[tid] = s;
  __syncthreads();
  if (tid == 0) {
    uint32_t cum = 0; int cidx = -1;
    for (int cc = 255; cc >= 0; --cc) {
      if (cum + ps[cc] >= KTOP) { cidx = cc; break; }
      cum += ps[cc];
    }
    if (cidx < 0) { thr[n] = 0u; return; }
    int b = cidx*64+63;
    for (; b >= cidx*64; --b) { cum += hb[b]; if (cum >= KTOP) break; }
    thr[n] = (uint32_t)(b < 0 ? 0 : b);
  }
}

// ---------------- compact: float4 loads + block-aggregated atomic ----------------
__global__ __launch_bounds__(256) void k_compact(const float* __restrict__ obj,
                                                 const uint32_t* __restrict__ thr,
                                                 uint64_t* __restrict__ cand,
                                                 uint32_t* __restrict__ cnt) {
  __shared__ uint32_t wtot[4];
  __shared__ uint32_t gbase;
  int n = blockIdx.x / CBLK, c = blockIdx.x % CBLK;
  int tid = threadIdx.x, wv = tid >> 6, lane = tid & 63;
  int q = c*256 + tid;                 // float4 index within batch
  uint32_t th = thr[n];
  bool hit0=false, hit1=false, hit2=false, hit3=false;
  uint32_t bits[4], fidx[4];
  if (q < NQ4) {
    float4 v = ((const float4*)(obj + (size_t)n*MTOT))[q];
    #pragma unroll
    for (int k = 0; k < 4; ++k) {
      float x = (&v.x)[k];
      uint32_t b = __float_as_uint(sigmoid_ref(x));
      uint32_t bin = b >> 16; if (bin > NBINS-1) bin = NBINS-1;
      bits[k] = b;
      int rem = q*4 + k;               // element index within batch
      int hw = rem % (HDIM*WDIM);
      int a  = rem / (HDIM*WDIM);
      fidx[k] = (uint32_t)(hw*AANCH + a);
      bool hk = (bin >= th);
      if (k == 0) hit0 = hk; else if (k == 1) hit1 = hk;
      else if (k == 2) hit2 = hk; else hit3 = hk;
    }
  }
  unsigned long long m0 = __ballot(hit0);
  unsigned long long m1 = __ballot(hit1);
  unsigned long long m2 = __ballot(hit2);
  unsigned long long m3 = __ballot(hit3);
  if (lane == 0)
    wtot[wv] = (uint32_t)(__popcll(m0)+__popcll(m1)+__popcll(m2)+__popcll(m3));
  __syncthreads();
  if (tid == 0) {
    uint32_t t0 = wtot[0], t1 = wtot[1], t2 = wtot[2], t3 = wtot[3];
    uint32_t tot = t0+t1+t2+t3;
    gbase = tot ? atomicAdd(&cnt[n], tot) : 0u;
    wtot[0] = 0; wtot[1] = t0; wtot[2] = t0+t1; wtot[3] = t0+t1+t2;
  }
  __syncthreads();
  uint32_t base = gbase + wtot[wv];
  unsigned long long below = (1ull << lane) - 1ull;
  uint32_t off = 0;
  bool hits[4] = {hit0, hit1, hit2, hit3};
  unsigned long long ms[4] = {m0, m1, m2, m3};
  #pragma unroll
  for (int k = 0; k < 4; ++k) {
    if (hits[k]) {
      uint32_t p = base + off + (uint32_t)__popcll(ms[k] & below);
      if (p < CAND_CAP)
        cand[(size_t)n*CAND_CAP + p] = ((uint64_t)bits[k] << 32) | (uint32_t)(~fidx[k]);
    }
    off += (uint32_t)__popcll(ms[k]);
  }
}

// ---------------- bitonic sort (2048) + fused decode epilogue ----------------
__global__ __launch_bounds__(1024) void k_sortdec(const uint64_t* __restrict__ cand,
                                                  const uint32_t* __restrict__ cnt,
                                                  const float* __restrict__ breg,
                                                  const float* __restrict__ anch,
                                                  float* __restrict__ prop,
                                                  float* __restrict__ score,
                                                  float* __restrict__ corn,
                                                  float* __restrict__ area,
                                                  float4* __restrict__ xyr,
                                                  uint32_t* __restrict__ validf) {
  __shared__ uint64_t sk[CAND_CAP];
  int n = blockIdx.x, tid = threadIdx.x;
  uint32_t c = cnt[n]; if (c > CAND_CAP) c = CAND_CAP;
  #pragma unroll
  for (int i = tid; i < CAND_CAP; i += 1024)
    sk[i] = (i < (int)c) ? cand[(size_t)n*CAND_CAP + i] : 0ull;
  __syncthreads();
  for (int len = 2; len <= CAND_CAP; len <<= 1) {
    for (int str = len >> 1; str > 0; str >>= 1) {
      #pragma unroll
      for (int i = tid; i < CAND_CAP; i += 1024) {
        int j = i ^ str;
        if (j > i) {
          bool up = ((i & len) == 0);
          uint64_t x = sk[i], y = sk[j];
          if ((x > y) == up) { sk[i] = y; sk[j] = x; }
        }
      }
      __syncthreads();
    }
  }
  // ---- decode entry `tid` (rank tid, descending) ----
  if (tid < KTOP) {
#pragma clang fp contract(off)
    int t = n*KTOP + tid;
    uint64_t key = sk[CAND_CAP-1-tid];
    uint32_t idx = ~(uint32_t)(key & 0xFFFFFFFFull);
    float s = __uint_as_float((uint32_t)(key >> 32));
    int a = idx % AANCH, pos = idx / AANCH;
    int w = pos % WDIM, h = pos / WDIM;
    float d[5], an[5];
    #pragma unroll
    for (int j = 0; j < 5; ++j)
      d[j] = breg[((n*(AANCH*5) + (a*5+j))*HDIM + h)*WDIM + w];
    #pragma unroll
    for (int j = 0; j < 5; ++j)
      an[j] = anch[((size_t)n*MTOT + idx)*5 + j];
    const float CLIP = 4.135166556742356f;           // log(1000/16)
    float dw = fminf(d[2], CLIP), dh = fminf(d[3], CLIP);
    float x  = d[0]*an[2] + an[0];
    float y  = d[1]*an[3] + an[1];
    float bw = expf(dw)*an[2];
    float bh = expf(dh)*an[3];
    float th = an[4] + d[4]*57.29577951308232f;      // 180/pi
    prop[t*5+0]=x; prop[t*5+1]=y; prop[t*5+2]=bw; prop[t*5+3]=bh; prop[t*5+4]=th;
    score[t] = s;
    validf[t] = (bw >= 4.0f && bh >= 4.0f) ? 1u : 0u;
    area[t] = bw*bh;
    float r = 0.5f*sqrtf(bw*bw + bh*bh);
    xyr[t] = make_float4(x, y, r, 0.0f);
    float ang = th * 0.017453292519943295f;          // pi/180
    float cs = cosf(ang), sn = sinf(ang);
    float hw2 = bw*0.5f, hh2 = bh*0.5f;
    const float sx[4] = {1.f,-1.f,-1.f,1.f};
    const float sy[4] = {1.f,1.f,-1.f,-1.f};
    #pragma unroll
    for (int k = 0; k < 4; ++k) {
      float dxk = sx[k]*hw2, dyk = sy[k]*hh2;
      float cx = (x + cs*dxk) - sn*dyk;
      float cy = (y + sn*dxk) + cs*dyk;
      corn[t*8 + k*2 + 0] = cx;
      corn[t*8 + k*2 + 1] = cy;
    }
  }
}

// ---------------- Sutherland-Hodgman, register-resident ----------------
__device__ __forceinline__ float quad_inter_area(const float* __restrict__ ca,
                                                 const float* __restrict__ cb) {
#pragma clang fp contract(off)
  float px[8], py[8];
  int n = 4;
  #pragma unroll
  for (int i = 0; i < 4; ++i) { px[i] = ca[2*i]; py[i] = ca[2*i+1]; }
  #pragma unroll
  for (int i = 4; i < 8; ++i) { px[i] = 0.0f; py[i] = 0.0f; }
  #pragma unroll
  for (int e = 0; e < 4; ++e) {
    float p1x = cb[2*e], p1y = cb[2*e+1];
    int e2 = (e+1)&3;
    float dx = cb[2*e2] - p1x, dy = cb[2*e2+1] - p1y;
    float sd[8];
    #pragma unroll
    for (int i = 0; i < 8; ++i)
      sd[i] = dx*(py[i]-p1y) - dy*(px[i]-p1x);   // only i<n consumed
    float qx[8], qy[8];
    #pragma unroll
    for (int i = 0; i < 8; ++i) { qx[i] = 0.0f; qy[i] = 0.0f; }
    int m = 0;
    #pragma unroll
    for (int i = 0; i < 8; ++i) {
      if (i < n) {
        bool wrap = !(i+1 < n);
        float sdi = sd[i];
        float sdn = wrap ? sd[0] : sd[(i+1)&7];
        float pnx = wrap ? px[0] : px[(i+1)&7];
        float pny = wrap ? py[0] : py[(i+1)&7];
        bool ini = sdi >= 0.0f, inn = sdn >= 0.0f;
        if (ini) {
          float vx = px[i], vy = py[i];
          #pragma unroll
          for (int k = 0; k < 8; ++k) if (m == k) { qx[k] = vx; qy[k] = vy; }
          ++m;
        }
        if (ini != inn) {
          float den = sdi - sdn;
          float dd = (fabsf(den) < 1e-12f) ? 1e-12f : den;
          float tt = sdi/dd;
          float vx = px[i] + tt*(pnx - px[i]);
          float vy = py[i] + tt*(pny - py[i]);
          #pragma unroll
          for (int k = 0; k < 8; ++k) if (m == k) { qx[k] = vx; qy[k] = vy; }
          ++m;
        }
      }
    }
    n = m;
    #pragma unroll
    for (int i = 0; i < 8; ++i) { px[i] = qx[i]; py[i] = qy[i]; }
  }
  float ssum = 0.0f;
  #pragma unroll
  for (int i = 0; i < 8; ++i) {
    if (i < n) {
      bool wrap = !(i+1 < n);
      float pnx = wrap ? px[0] : px[(i+1)&7];
      float pny = wrap ? py[0] : py[(i+1)&7];
      ssum += px[i]*pny - pnx*py[i];
    }
  }
  return 0.5f*fabsf(ssum);
}

// ---------------- fused circle-test + clip; xyr staged in LDS; 4 rows/block ----------------
__global__ __launch_bounds__(256) void k_iou(const float4* __restrict__ xyr,
                                             const float* __restrict__ corn,
                                             const float* __restrict__ area,
                                             uint64_t* __restrict__ maskT) {
  __shared__ float4 sxyr[KTOP];            // 16000 B, this batch's boxes
  __shared__ uint32_t q[QCAP];             // 16384 B
  __shared__ uint32_t qcnt;
  __shared__ uint32_t mrow32[IOU_WPB*2];   // 4 rows x 16 words x 2 halves
  __shared__ float ca[IOU_ROWS*8];         // own rows' corners
  __shared__ float aa[IOU_ROWS];
  int n = blockIdx.x / IOU_BPB;
  int wbase = (blockIdx.x % IOU_BPB) * IOU_WPB;
  int i0 = wbase >> 4;                     // first owned i-row
  int tid = threadIdx.x, wv = tid >> 6, lane = tid & 63;
  // stage
  for (int t = tid; t < KTOP; t += 256) sxyr[t] = xyr[n*KTOP + t];
  if (tid == 0) qcnt = 0;
  if (tid < IOU_WPB*2) mrow32[tid] = 0;
  if (tid >= 128 && tid < 128 + IOU_ROWS*8)
    ca[tid-128] = corn[(size_t)(n*KTOP + i0)*8 + (tid-128)];
  if (tid >= 160 && tid < 160 + IOU_ROWS)
    aa[tid-160] = area[n*KTOP + i0 + (tid-160)];
  __syncthreads();
  // scan: 16 words per wave, all LDS reads
  for (int w = wv; w < IOU_WPB; w += 4) {
    int word = wbase + w;
    int i = word >> 4;               // word / NWORDS
    int jb = word & 15;              // word % NWORDS
    if (jb*64 + 63 <= i) continue;   // no j > i in this word
    int j = jb*64 + lane;
    bool hit = false;
    if (j > i && j < KTOP) {
      float4 a = sxyr[i];            // wave-uniform LDS broadcast
      float4 b = sxyr[j];
      float dx = a.x - b.x, dy = a.y - b.y;
      float rs = a.z + b.z;
      hit = (dx*dx + dy*dy) <= rs*rs*1.0001f;
    }
    unsigned long long bal = __ballot(hit);
    if (!bal) continue;
    int tot = __popcll(bal);
    int leader = __ffsll(bal) - 1;
    uint32_t base = 0;
    if (lane == leader) base = atomicAdd(&qcnt, (uint32_t)tot);
    base = __shfl(base, leader);
    if (hit) {
      int pos = __popcll(bal & ((1ull << lane) - 1ull));
      q[base + pos] = ((uint32_t)i << 10) | (uint32_t)j;
    }
  }
  __syncthreads();
  uint32_t cnt = qcnt;
  for (uint32_t t = tid; t < cnt; t += 256) {
    uint32_t code = q[t];
    int i = code >> 10, j = code & 1023;
    int bj = n*KTOP + j;
    float inter = quad_inter_area(&ca[(i - i0)*8], &corn[(size_t)bj*8]);
    float uni = (aa[i - i0] + area[bj]) - inter;
    if (inter / fmaxf(uni, 1e-8f) > NMS_TH)
      atomicOr(&mrow32[((i - i0)*NWORDS + (j >> 6))*2 + ((j >> 5) & 1)],
               1u << (j & 31));
  }
  __syncthreads();
  // store transposed: maskT[n][l][row] (disjoint cells, full overwrite)
  uint64_t* dstT = &maskT[(size_t)n*NWORDS*KTOP];
  for (int t = tid; t < IOU_WPB; t += 256) {
    int r = t >> 4, l = t & 15;
    dstT[(size_t)l*KTOP + i0 + r] =
      (uint64_t)mrow32[(r*NWORDS + l)*2] | ((uint64_t)mrow32[(r*NWORDS + l)*2 + 1] << 32);
  }
}

// ---------------- blocked greedy NMS: no staging, readlane diag, prefetch ----------------
__global__ __launch_bounds__(256) void k_nms(const uint32_t* __restrict__ validf,
                                             const uint64_t* __restrict__ maskT,
                                             const float* __restrict__ prop,
                                             const float* __restrict__ score,
                                             float* __restrict__ out) {
  __shared__ uint64_t kw[NWORDS];
  int n = blockIdx.x;
  int tid = threadIdx.x, wv = tid >> 6, lane = tid & 63;
  const uint64_t* MT = &maskT[(size_t)n*NWORDS*KTOP];

  // wave0: preload all 16 diag words (lane holds row b*64+lane's word b)
  uint64_t dreg[NWORDS];
  if (wv == 0) {
    #pragma unroll
    for (int b = 0; b < NWORDS; ++b) {
      int row = b*64 + lane;
      dreg[b] = MT[(size_t)b*KTOP + (row < KTOP ? row : 0)];
    }
    #pragma unroll
    for (int w = 0; w < NWORDS; ++w) {
      int k = w*64 + lane;
      uint32_t v = (k < KTOP) ? validf[n*KTOP + k] : 0u;
      unsigned long long bm = __ballot(v != 0u);
      if (lane == 0) kw[w] = (uint64_t)bm;
    }
  }
  __syncthreads();

  // cross-apply double buffer: phase b uses rows b*64+lane at words l=b+1+wv+4k
  uint64_t cur0=0, cur1=0, cur2=0, cur3=0;
  {
    int row = lane;            // phase 0 rows
    int l0 = 1 + wv;
    cur0 = (l0    < NWORDS) ? MT[(size_t)(l0   )*KTOP + row] : 0ull;
    cur1 = (l0+4  < NWORDS) ? MT[(size_t)(l0+4 )*KTOP + row] : 0ull;
    cur2 = (l0+8  < NWORDS) ? MT[(size_t)(l0+8 )*KTOP + row] : 0ull;
    cur3 = (l0+12 < NWORDS) ? MT[(size_t)(l0+12)*KTOP + row] : 0ull;
  }

  for (int b = 0; b < NWORDS; ++b) {
    // --- diag resolve (wave 0): readlane + branchless SALU chain, uniform ---
    if (wv == 0) {
      uint64_t alive = kw[b];
      uint32_t dlo = (uint32_t)dreg[b], dhi = (uint32_t)(dreg[b] >> 32);
      #pragma unroll
      for (int i = 0; i < 64; ++i) {
        uint32_t lo = __builtin_amdgcn_readlane(dlo, i);
        uint32_t hi = __builtin_amdgcn_readlane(dhi, i);
        uint64_t d = ((uint64_t)hi << 32) | lo;
        uint64_t m = (uint64_t)0 - ((alive >> i) & 1ull);
        alive &= ~(d & m);
      }
      if (lane == 0) kw[b] = alive;
    }
    // --- prefetch next phase's apply rows (alive-independent) ---
    uint64_t nxt0=0, nxt1=0, nxt2=0, nxt3=0;
    if (b + 2 < NWORDS) {
      int row = (b+1)*64 + lane;     // <= 959, in range
      int l0 = b + 2 + wv;
      nxt0 = (l0    < NWORDS) ? MT[(size_t)(l0   )*KTOP + row] : 0ull;
      nxt1 = (l0+4  < NWORDS) ? MT[(size_t)(l0+4 )*KTOP + row] : 0ull;
      nxt2 = (l0+8  < NWORDS) ? MT[(size_t)(l0+8 )*KTOP + row] : 0ull;
      nxt3 = (l0+12 < NWORDS) ? MT[(size_t)(l0+12)*KTOP + row] : 0ull;
    }
    __syncthreads();
    if (b < NWORDS-1) {
      uint64_t alive = kw[b];
      uint64_t me = (uint64_t)0 - ((alive >> lane) & 1ull);
      uint64_t mv0 = cur0 & me, mv1 = cur1 & me, mv2 = cur2 & me, mv3 = cur3 & me;
      #pragma unroll
      for (int s = 1; s < 64; s <<= 1) {
        mv0 |= __shfl_xor(mv0, s);
        mv1 |= __shfl_xor(mv1, s);
        mv2 |= __shfl_xor(mv2, s);
        mv3 |= __shfl_xor(mv3, s);
      }
      if (lane == 0) {
        int l0 = b + 1 + wv;
        if (l0    < NWORDS) kw[l0   ] &= ~mv0;
        if (l0+4  < NWORDS) kw[l0+4 ] &= ~mv1;
        if (l0+8  < NWORDS) kw[l0+8 ] &= ~mv2;
        if (l0+12 < NWORDS) kw[l0+12] &= ~mv3;
      }
      __syncthreads();
    }
    cur0=nxt0; cur1=nxt1; cur2=nxt2; cur3=nxt3;
  }

  // rank <= POSTN trim (thread 0), then all threads write output
  if (tid == 0) {
    int prev = 0;
    #pragma unroll
    for (int t = 0; t < NWORDS; ++t) {
      uint64_t wrd = kw[t];
      int pc = __popcll(wrd);
      if (prev >= POSTN) wrd = 0;
      else if (prev + pc > POSTN) {
        int allow = POSTN - prev;
        while (__popcll(wrd) > allow) wrd &= ~(1ull << (63 - __clzll(wrd)));
      }
      prev += __popcll(wrd);
      kw[t] = wrd;
    }
  }
  __syncthreads();
  for (int k = tid; k < KTOP; k += 256) {
    bool bb = (kw[k>>6] >> (k&63)) & 1ull;
    float f = bb ? 1.0f : 0.0f;
    int t = n*KTOP + k;
    #pragma unroll
    for (int c = 0; c < 5; ++c) out[t*6 + c] = prop[t*5 + c] * f;
    out[t*6 + 5] = score[t] * f;
  }
}

extern "C" void kernel_launch(void* const* d_in, const int* in_sizes, int n_in,
                              void* d_out, int out_size, void* d_ws, size_t ws_size,
                              hipStream_t stream) {
  const float* obj  = (const float*)d_in[0];
  const float* breg = (const float*)d_in[1];
  const float* anch = (const float*)d_in[2];
  float* out = (float*)d_out;
  char* ws = (char*)d_ws;

  uint32_t* hist  = (uint32_t*)(ws + OFF_HIST);
  uint32_t* cnt   = (uint32_t*)(ws + OFF_CNT);
  uint32_t* thr   = (uint32_t*)(ws + OFF_THR);
  uint64_t* cand  = (uint64_t*)(ws + OFF_CAND);
  float*    prop  = (float*)(ws + OFF_PROP);
  float*    score = (float*)(ws + OFF_SCORE);
  float*    corn  = (float*)(ws + OFF_CORN);
  float*    area  = (float*)(ws + OFF_AREA);
  uint32_t* validf= (uint32_t*)(ws + OFF_VALID);
  float4*   xyr   = (float4*)(ws + OFF_XYR);
  uint64_t* maskT = (uint64_t*)(ws + OFF_MASK);

  hipMemsetAsync(ws, 0, OFF_CAND, stream);   // hist + cnt + thr

  k_hist   <<<NBATCH*BPB, 256, 0, stream>>>(obj, hist);
  k_thresh <<<NBATCH, 256, 0, stream>>>(hist, thr);
  k_compact<<<NBATCH*CBLK, 256, 0, stream>>>(obj, thr, cand, cnt);
  k_sortdec<<<NBATCH, 1024, 0, stream>>>(cand, cnt, breg, anch, prop, score, corn, area, xyr, validf);
  k_iou    <<<NBATCH*IOU_BPB, 256, 0, stream>>>(xyr, corn, area, maskT);
  k_nms    <<<NBATCH, 256, 0, stream>>>(validf, maskT, prop, score, out);
}